// Round 10
// baseline (417.685 us; speedup 1.0000x reference)
//
#include <hip/hip_runtime.h>
#include <hip/hip_bf16.h>
#include <stdint.h>

typedef __bf16 bf16;
typedef __bf16 bf16x8 __attribute__((ext_vector_type(8)));
typedef __bf16 bf16x4 __attribute__((ext_vector_type(4)));
typedef float f32x4 __attribute__((ext_vector_type(4)));
typedef float f32x16 __attribute__((ext_vector_type(16)));

#define B_ 2
#define L_ 2048
#define E_ 2048
#define H_ 16
#define HKV_ 2
#define G_ 8
#define D_ 128
#define SPAST_ 2048
#define S_ 4096
#define EKV_ 256

#define MFMA16(a, b, c) __builtin_amdgcn_mfma_f32_16x16x32_bf16(a, b, c, 0, 0, 0)
#define MFMA32(a, b, c) __builtin_amdgcn_mfma_f32_32x32x16_bf16(a, b, c, 0, 0, 0)

__device__ __forceinline__ void gload16(const bf16* g, bf16* l) {
  __builtin_amdgcn_global_load_lds(
      (__attribute__((address_space(1))) void*)g,
      (__attribute__((address_space(3))) void*)l, 16, 0, 0);
}

// ---------------- f32 -> bf16 conversion ----------------
__global__ void cvt_kernel(const float* __restrict__ src, bf16* __restrict__ dst, int n) {
  int i = (blockIdx.x * 256 + threadIdx.x) * 4;
  if (i >= n) return;
  float4 v = *(const float4*)(src + i);
  bf16x4 o;
  o[0] = (bf16)v.x; o[1] = (bf16)v.y; o[2] = (bf16)v.z; o[3] = (bf16)v.w;
  *(bf16x4*)(dst + i) = o;
}

// ---------------- trig table ----------------
__global__ void trig_kernel(const int* __restrict__ offp, float2* __restrict__ trig) {
  int l = blockIdx.x, j = threadIdx.x;  // 64 threads
  float inv = exp2f(-(float)j * (13.287712379549449f / 64.0f));  // log2(10000)
  float ang = (float)(*offp + l) * inv;
  trig[l * 64 + j] = make_float2(cosf(ang), sinf(ang));
}

// ---------------- NT GEMM: C(M,N) = A(M,K) @ Bw(N,K)^T + bias (2-phase dbuf) ----------------
template <int OUTF32>
__global__ __launch_bounds__(256) void gemm_nt(const bf16* __restrict__ A,
                                               const bf16* __restrict__ Bw,
                                               const float* __restrict__ bias,
                                               void* __restrict__ Cout,
                                               int M, int N, int K) {
  __shared__ bf16 As[2 * 128 * 64];
  __shared__ bf16 Bs[2 * 128 * 64];
  const int tid = threadIdx.x;
  const int wid = tid >> 6, lane = tid & 63;
  const int ln15 = lane & 15, lq = lane >> 4;
  const int row0 = blockIdx.x * 128, col0 = blockIdx.y * 128;
  const int wr = wid >> 1, wc = wid & 1;
  f32x4 acc[4][4] = {};
  char* AsB = (char*)As;
  char* BsB = (char*)Bs;

  auto STAGE = [&](int buf, int k0) {
    char* ad = AsB + buf * 16384;
    char* bd = BsB + buf * 16384;
#pragma unroll
    for (int j = 0; j < 4; j++) {
      int cid = j * 256 + tid;
      int r = cid >> 3, c = cid & 7;
      int csw = (c ^ (r & 7)) << 3;
      gload16(A + (size_t)(row0 + r) * K + k0 + csw, (bf16*)(ad + (j * 256 + wid * 64) * 16));
      gload16(Bw + (size_t)(col0 + r) * K + k0 + csw, (bf16*)(bd + (j * 256 + wid * 64) * 16));
    }
  };

  STAGE(0, 0);
  __syncthreads();
  int cur = 0;
  for (int k0 = 0; k0 < K; k0 += 64) {
    if (k0 + 64 < K) STAGE(cur ^ 1, k0 + 64);
    char* ac = AsB + cur * 16384;
    char* bc = BsB + cur * 16384;
    bf16x8 af[4][2], bfm[4][2];
#pragma unroll
    for (int m = 0; m < 4; m++) {
#pragma unroll
      for (int kk = 0; kk < 2; kk++) {
        int Ra = wr * 64 + m * 16 + ln15;
        int Rb = wc * 64 + m * 16 + ln15;
        int c = (kk << 2) + lq;
        af[m][kk] = *(const bf16x8*)(ac + Ra * 128 + ((c ^ (Ra & 7)) << 4));
        bfm[m][kk] = *(const bf16x8*)(bc + Rb * 128 + ((c ^ (Rb & 7)) << 4));
      }
    }
    __builtin_amdgcn_s_setprio(1);
#pragma unroll
    for (int m = 0; m < 4; m++)
#pragma unroll
      for (int n = 0; n < 4; n++)
#pragma unroll
        for (int kk = 0; kk < 2; kk++)
          acc[m][n] = MFMA16(af[m][kk], bfm[n][kk], acc[m][n]);
    __builtin_amdgcn_s_setprio(0);
    __syncthreads();
    cur ^= 1;
  }
#pragma unroll
  for (int m = 0; m < 4; m++) {
    int gr0 = row0 + wr * 64 + m * 16 + 4 * lq;
#pragma unroll
    for (int n = 0; n < 4; n++) {
      int gc = col0 + wc * 64 + n * 16 + ln15;
      float bv = bias ? bias[gc] : 0.0f;
#pragma unroll
      for (int reg = 0; reg < 4; reg++) {
        float v = acc[m][n][reg] + bv;
        size_t idx = (size_t)(gr0 + reg) * N + gc;
        if (OUTF32)
          ((float*)Cout)[idx] = v;
        else
          ((bf16*)Cout)[idx] = (bf16)v;
      }
    }
  }
}

// ---------------- RoPE on Q (vectorized bf16x8), fold softmax scale*log2e ----------------
__global__ void rope_q_kernel(const bf16* __restrict__ q_lin, const float2* __restrict__ trig,
                              bf16* __restrict__ qbuf) {
  int bl = blockIdx.x * 2 + (threadIdx.x >> 7);  // grid = B*L/2
  int b = bl >> 11, l = bl & 2047;
  int u = threadIdx.x & 127;
  int h = u >> 3, j0 = (u & 7) * 8;
  const float QS = 0.08838834764831845f * 1.4426950408889634f;  // 1/sqrt(128) * log2(e)
  const bf16* src = q_lin + (size_t)bl * E_ + h * D_ + j0;
  bf16x8 x1 = *(const bf16x8*)(src);
  bf16x8 x2 = *(const bf16x8*)(src + 64);
  bf16x8 o1, o2;
#pragma unroll
  for (int e = 0; e < 8; e++) {
    float2 cs = trig[l * 64 + j0 + e];
    float a = (float)x1[e], c = (float)x2[e];
    o1[e] = (bf16)((a * cs.x - c * cs.y) * QS);
    o2[e] = (bf16)((c * cs.x + a * cs.y) * QS);
  }
  size_t o = ((size_t)(b * H_ + h) * L_ + l) * D_ + j0;
  *(bf16x8*)(qbuf + o) = o1;
  *(bf16x8*)(qbuf + o + 64) = o2;
}

// ---------------- build k_all (B,HKV,S,D) ----------------
__global__ void build_k_kernel(const float* __restrict__ k_cache, const bf16* __restrict__ k_lin,
                               const float2* __restrict__ trig, bf16* __restrict__ k_all) {
  int d = threadIdx.x;  // 128
  int s = blockIdx.x;
  int bz = blockIdx.y;  // b*HKV + hkv
  size_t oidx = ((size_t)bz * S_ + s) * D_ + d;
  if (s < SPAST_) {
    k_all[oidx] = (bf16)k_cache[((size_t)bz * SPAST_ + s) * D_ + d];
  } else {
    int l = s - SPAST_;
    int b = bz >> 1, kh = bz & 1;
    int j = d & 63;
    float2 cs = trig[l * 64 + j];
    size_t base = (size_t)(b * L_ + l) * EKV_ + kh * D_;
    float x1 = (float)k_lin[base + j];
    float x2 = (float)k_lin[base + 64 + j];
    float v = (d < 64) ? (x1 * cs.x - x2 * cs.y) : (x2 * cs.x + x1 * cs.y);
    k_all[oidx] = (bf16)v;
  }
}

// ---------------- build transposed V: vtall (B,HKV,D,S) (vectorized) ----------------
__global__ void build_vt_kernel(const float* __restrict__ v_cache, const bf16* __restrict__ v_lin,
                                bf16* __restrict__ vtall) {
  __shared__ float tile[64][68];
  int s0 = blockIdx.x * 64;
  int d0 = blockIdx.y * 64;
  int bz = blockIdx.z;
  int b = bz >> 1, kh = bz & 1;
#pragma unroll
  for (int it = 0; it < 4; it++) {
    int idx = it * 256 + threadIdx.x;  // 0..1023
    int ss = idx >> 4, dd0 = (idx & 15) * 4;
    int s = s0 + ss;
    float4 v;
    if (s < SPAST_) {
      v = *(const float4*)(v_cache + ((size_t)bz * SPAST_ + s) * D_ + d0 + dd0);
    } else {
      bf16x4 t = *(const bf16x4*)(v_lin + (size_t)(b * L_ + (s - SPAST_)) * EKV_ + kh * D_ + d0 + dd0);
      v = make_float4((float)t[0], (float)t[1], (float)t[2], (float)t[3]);
    }
    tile[ss][dd0] = v.x; tile[ss][dd0 + 1] = v.y;
    tile[ss][dd0 + 2] = v.z; tile[ss][dd0 + 3] = v.w;
  }
  __syncthreads();
#pragma unroll
  for (int it = 0; it < 4; it++) {
    int idx = it * 256 + threadIdx.x;
    int dd = idx >> 4, ss0 = (idx & 15) * 4;
    bf16x4 o;
#pragma unroll
    for (int e = 0; e < 4; e++) o[e] = (bf16)tile[ss0 + e][dd];
    *(bf16x4*)(vtall + ((size_t)bz * D_ + d0 + dd) * S_ + s0 + ss0) = o;
  }
}

// ---------------- flash attention, split-K-across-blocks variant ----------------
// grid (16, 32, 2) x 256 threads. z selects key half; each block is the proven R6 loop over
// 32-key chunks (LDS 32KB -> 4 blocks/CU co-residency; 1024 blocks = 4/CU = 4 waves/SIMD).
// Writes f32 partials (O, m, l); attn_merge_kernel combines.
__global__ __launch_bounds__(256, 4) void attn_split_kernel(const bf16* __restrict__ qbuf,
                                                            const bf16* __restrict__ k_all,
                                                            const bf16* __restrict__ vtall,
                                                            float* __restrict__ part_o,
                                                            float* __restrict__ part_ml) {
  __shared__ bf16 Ks[2 * 32 * 128];  // [key][d] 256B rows, swizzled 16B slots (8KB/buf)
  __shared__ bf16 Vs[2 * 32 * 128];  // row r = d-quad {4r..4r+3} x 32 keys (8KB/buf)
  const int tid = threadIdx.x;
  const int wid = tid >> 6, lane = tid & 63;
  const int l31 = lane & 31, h = lane >> 5;
  const int xq = ((blockIdx.y >> 4) & 1) ? (15 - (int)blockIdx.x) : (int)blockIdx.x;
  const int q0 = xq * 128;
  const int bh = blockIdx.y;
  const int z = blockIdx.z;
  const int b = bh / H_, hh = bh % H_;
  const int hkv = hh / G_;
  const bf16* kb = k_all + (size_t)(b * HKV_ + hkv) * S_ * D_;
  const bf16* vb = vtall + (size_t)(b * HKV_ + hkv) * D_ * S_;
  const int qw = q0 + wid * 32;
  // staging: 512 K slots + 512 V slots per chunk over 256 threads (2+2 each)
  const int r0 = tid >> 4;                       // 0..15
  const int cl0 = (tid & 15) ^ (r0 & 15);        // logical 16B slot
  const bf16* krow = kb + r0 * D_ + cl0 * 8;
  const bf16* vrow = vb + (size_t)(4 * r0 + (cl0 >> 2)) * S_ + (cl0 & 3) * 8;
  const int dstoff = (wid * 64) * 16;
  // Q fragments (B operand): col=q=l31, k-dim d = ks*16 + 8h + i
  bf16x8 qf[8];
  {
    const bf16* qp = qbuf + ((size_t)(b * H_ + hh) * L_ + qw + l31) * D_ + h * 8;
#pragma unroll
    for (int ks = 0; ks < 8; ks++) qf[ks] = *(const bf16x8*)(qp + ks * 16);
  }
  f32x16 acc[4] = {};
  float mr = -3e38f, lr = 0.f;

  auto STAGE = [&](int buf, int s0) {
    char* kd = (char*)Ks + buf * 8192 + dstoff;
    char* vd = (char*)Vs + buf * 8192 + dstoff;
    size_t ko = (size_t)s0 << 7;  // s0 * D_
    gload16(krow + ko, (bf16*)(kd));
    gload16(krow + ko + 16 * D_, (bf16*)(kd + 4096));
    gload16(vrow + s0, (bf16*)(vd));
    gload16(vrow + s0 + (size_t)64 * S_, (bf16*)(vd + 4096));
  };

  const int nch2 = 2 * xq + 34;       // 32-key chunks per z ((4xq+68)/2)
  const int zb = z * nch2;
  const int smax_w = qw + 32 + SPAST_;

  STAGE(0, zb << 5);
  __syncthreads();
  int cur = 0;
  for (int i = 0; i < nch2; ++i) {
    int s0 = (zb + i) << 5;
    if (i + 1 < nch2) STAGE(cur ^ 1, s0 + 32);  // prefetch own next chunk
    if (s0 < smax_w) {
      char* kcur = (char*)Ks + cur * 8192;
      char* vcur = (char*)Vs + cur * 8192;
      // ---- swapped QK^T: lane holds q=l31, keys s0 + (r&3)+8*(r>>2)+4h
      f32x16 st;
      {
        f32x16 a = {};
        __builtin_amdgcn_s_setprio(1);
#pragma unroll
        for (int ks = 0; ks < 8; ks++) {
          int cl = 2 * ks + h;
          bf16x8 kf = *(const bf16x8*)(kcur + l31 * 256 + ((cl ^ (l31 & 15)) << 4));
          a = MFMA32(kf, qf[ks], a);
        }
        __builtin_amdgcn_s_setprio(0);
        st = a;
      }
      // ---- causal mask (z=1 diagonal chunks only)
      if (s0 + 31 > qw + SPAST_) {
        int q = qw + l31;
#pragma unroll
        for (int r = 0; r < 16; r++) {
          int key = s0 + (r & 3) + 8 * (r >> 2) + 4 * h;
          if (key > q + SPAST_) st[r] = -1e30f;
        }
      }
      // ---- online softmax: in-lane tree + 1 half-swap
      float mt = fmaxf(st[0], st[1]);
#pragma unroll
      for (int r = 2; r < 16; r++) mt = fmaxf(mt, st[r]);
      mt = fmaxf(mt, __shfl_xor(mt, 32));
      if (__any(mt - mr > 8.0f)) {  // T13 defer-max
        float mn = fmaxf(mr, mt);
        float fac = exp2f(mr - mn);
        mr = mn;
        lr *= fac;
#pragma unroll
        for (int dt = 0; dt < 4; dt++) acc[dt] *= fac;
      }
      float s = 0.f;
#pragma unroll
      for (int r = 0; r < 16; r++) {
        float p = exp2f(st[r] - mr);
        st[r] = p;
        s += p;
      }
      s += __shfl_xor(s, 32);
      lr += s;
      // ---- P -> bf16 dwords + permlane32_swap (VDST.hi <-> VSRC.lo)
      uint32_t W[8];
#pragma unroll
      for (int j = 0; j < 8; j++)
        asm("v_cvt_pk_bf16_f32 %0, %1, %2" : "=v"(W[j]) : "v"(st[2 * j]), "v"(st[2 * j + 1]));
#pragma unroll
      for (int s4 = 0; s4 < 8; s4 += 4) {
        asm volatile("v_permlane32_swap_b32 %0, %1" : "+v"(W[s4 + 0]), "+v"(W[s4 + 2]));
        asm volatile("v_permlane32_swap_b32 %0, %1" : "+v"(W[s4 + 1]), "+v"(W[s4 + 3]));
      }
      // ---- PV: O^T = V^T x P^T
      __builtin_amdgcn_s_setprio(1);
#pragma unroll
      for (int dt = 0; dt < 4; dt++) {
        int r = dt * 8 + (l31 >> 2);
        int clb = 4 * (l31 & 3) + h;
        f32x16 a = acc[dt];
#pragma unroll
        for (int ks = 0; ks < 2; ks++) {
          int cl = clb + 2 * ks;
          bf16x8 vf = *(const bf16x8*)(vcur + r * 256 + ((cl ^ (r & 15)) << 4));
          union { uint32_t u[4]; bf16x8 v; } pb;
          pb.u[0] = W[ks * 4 + 0];
          pb.u[1] = W[ks * 4 + 1];
          pb.u[2] = W[ks * 4 + 2];
          pb.u[3] = W[ks * 4 + 3];
          a = MFMA32(vf, pb.v, a);
        }
        acc[dt] = a;
      }
      __builtin_amdgcn_s_setprio(0);
    }
    __syncthreads();
    cur ^= 1;
  }
  // ---- partial epilogue: O unnormalized f32 + (m,l); layout [z][bh][L][D]
  {
    int q = qw + l31;
    float* po = part_o + (((size_t)z * 32 + bh) * L_ + q) * D_;
#pragma unroll
    for (int dt = 0; dt < 4; dt++) {
      union { f32x16 v; f32x4 q4[4]; } u;
      u.v = acc[dt];
#pragma unroll
      for (int uu = 0; uu < 4; uu++)
        *(f32x4*)(po + dt * 32 + 8 * uu + 4 * h) = u.q4[uu];
    }
    if (h == 0) {
      float* pm = part_ml + (((size_t)z * 32 + bh) * L_ + q) * 2;
      pm[0] = mr;
      pm[1] = lr;
    }
  }
}

// ---------------- merge the two key-half partials ----------------
__global__ __launch_bounds__(256) void attn_merge_kernel(const float* __restrict__ part_o,
                                                         const float* __restrict__ part_ml,
                                                         bf16* __restrict__ attnout) {
  int gid = blockIdx.x * 256 + threadIdx.x;  // over B*H*L*(D/4) = 2,097,152
  int d4 = (gid & 31) * 4;
  int rest = gid >> 5;
  int q = rest & (L_ - 1);
  int bh = rest >> 11;  // 0..31
  size_t qi = (size_t)bh * L_ + q;
  const float* m0p = part_ml + qi * 2;
  const float* m1p = part_ml + ((size_t)32 * L_ + qi) * 2;
  float m0 = m0p[0], l0 = m0p[1], m1 = m1p[0], l1 = m1p[1];
  float m = fmaxf(m0, m1);
  float f0 = exp2f(m0 - m), f1 = exp2f(m1 - m);
  float linv = 1.0f / (l0 * f0 + l1 * f1);
  f32x4 o0 = *(const f32x4*)(part_o + qi * D_ + d4);
  f32x4 o1 = *(const f32x4*)(part_o + (size_t)32 * L_ * D_ + qi * D_ + d4);
  int b = bh >> 4, h = bh & 15;
  bf16x4 o;
#pragma unroll
  for (int e = 0; e < 4; e++) o[e] = (bf16)((o0[e] * f0 + o1[e] * f1) * linv);
  *(bf16x4*)(attnout + ((size_t)(b * L_ + q) * H_ + h) * D_ + d4) = o;
}

// ---------------- fallback: round-9 attn kernel (no split; used when ws is too small) ----------------
__global__ __launch_bounds__(256, 2) void attn_kernel(const bf16* __restrict__ qbuf,
                                                      const bf16* __restrict__ k_all,
                                                      const bf16* __restrict__ vtall,
                                                      bf16* __restrict__ attnout) {
  __shared__ bf16 Ks[2 * 64 * 128];
  __shared__ bf16 Vs[2 * 64 * 128];
  const int tid = threadIdx.x;
  const int wid = tid >> 6, lane = tid & 63;
  const int l31 = lane & 31, h = lane >> 5;
  const int xq = ((blockIdx.y >> 4) & 1) ? (15 - (int)blockIdx.x) : (int)blockIdx.x;
  const int q0 = xq * 128;
  const int bh = blockIdx.y;
  const int b = bh / H_, hh = bh % H_;
  const int hkv = hh / G_;
  const bf16* kb = k_all + (size_t)(b * HKV_ + hkv) * S_ * D_;
  const bf16* vb = vtall + (size_t)(b * HKV_ + hkv) * D_ * S_;
  const int qw = q0 + wid * 32;
  bf16x8 qf[8];
  {
    const bf16* qp = qbuf + ((size_t)(b * H_ + hh) * L_ + qw + l31) * D_ + h * 8;
#pragma unroll
    for (int ks = 0; ks < 8; ks++) qf[ks] = *(const bf16x8*)(qp + ks * 16);
  }
  f32x16 acc[4] = {};
  float mr = -3e38f, lr = 0.f;

  auto STAGE = [&](int buf, int s0) {
    char* kd = (char*)Ks + buf * 16384;
    char* vd = (char*)Vs + buf * 16384;
#pragma unroll
    for (int j = 0; j < 4; j++) {
      int cid = j * 256 + tid;
      int r = cid >> 4;
      int cl = (cid & 15) ^ (r & 15);
      gload16(kb + (size_t)(s0 + r) * D_ + cl * 8, (bf16*)(kd + (j * 256 + wid * 64) * 16));
      gload16(vb + (size_t)(2 * r + (cl >> 3)) * S_ + s0 + (cl & 7) * 8,
              (bf16*)(vd + (j * 256 + wid * 64) * 16));
    }
  };

  const int nchunk = (q0 + 128 + SPAST_) >> 6;
  const int smax_w = qw + 32 + SPAST_;

  STAGE(0, 0);
  __syncthreads();
  int cur = 0;
  for (int sc = 0; sc < nchunk; ++sc) {
    int s0 = sc << 6;
    if (sc + 1 < nchunk) STAGE(cur ^ 1, s0 + 64);
    if (s0 < smax_w) {
      char* kcur = (char*)Ks + cur * 16384;
      char* vcur = (char*)Vs + cur * 16384;
      f32x16 st[2];
      __builtin_amdgcn_s_setprio(1);
#pragma unroll
      for (int t = 0; t < 2; t++) {
        f32x16 a = {};
        int R = t * 32 + l31;
#pragma unroll
        for (int ks = 0; ks < 8; ks++) {
          int cl = 2 * ks + h;
          bf16x8 kf = *(const bf16x8*)(kcur + R * 256 + ((cl ^ (R & 15)) << 4));
          a = MFMA32(kf, qf[ks], a);
        }
        st[t] = a;
      }
      __builtin_amdgcn_s_setprio(0);
      if (s0 + 63 > qw + SPAST_) {
        int q = qw + l31;
#pragma unroll
        for (int t = 0; t < 2; t++)
#pragma unroll
          for (int r = 0; r < 16; r++) {
            int key = s0 + t * 32 + (r & 3) + 8 * (r >> 2) + 4 * h;
            if (key > q + SPAST_) st[t][r] = -1e30f;
          }
      }
      float mt = fmaxf(st[0][0], st[0][1]);
#pragma unroll
      for (int r = 2; r < 16; r++) mt = fmaxf(mt, st[0][r]);
#pragma unroll
      for (int r = 0; r < 16; r++) mt = fmaxf(mt, st[1][r]);
      mt = fmaxf(mt, __shfl_xor(mt, 32));
      if (__any(mt - mr > 8.0f)) {
        float mn = fmaxf(mr, mt);
        float fac = exp2f(mr - mn);
        mr = mn;
        lr *= fac;
#pragma unroll
        for (int dt = 0; dt < 4; dt++) acc[dt] *= fac;
      }
      float s = 0.f;
#pragma unroll
      for (int t = 0; t < 2; t++)
#pragma unroll
        for (int r = 0; r < 16; r++) {
          float p = exp2f(st[t][r] - mr);
          st[t][r] = p;
          s += p;
        }
      s += __shfl_xor(s, 32);
      lr += s;
      uint32_t W[2][8];
#pragma unroll
      for (int t = 0; t < 2; t++)
#pragma unroll
        for (int j = 0; j < 8; j++)
          asm("v_cvt_pk_bf16_f32 %0, %1, %2"
              : "=v"(W[t][j])
              : "v"(st[t][2 * j]), "v"(st[t][2 * j + 1]));
#pragma unroll
      for (int t = 0; t < 2; t++)
#pragma unroll
        for (int s4 = 0; s4 < 8; s4 += 4) {
          asm volatile("v_permlane32_swap_b32 %0, %1" : "+v"(W[t][s4 + 0]), "+v"(W[t][s4 + 2]));
          asm volatile("v_permlane32_swap_b32 %0, %1" : "+v"(W[t][s4 + 1]), "+v"(W[t][s4 + 3]));
        }
      __builtin_amdgcn_s_setprio(1);
#pragma unroll
      for (int dt = 0; dt < 4; dt++) {
        int r = dt * 16 + (l31 >> 1);
        int clb = 8 * (l31 & 1) + h;
        f32x16 a = acc[dt];
#pragma unroll
        for (int ks = 0; ks < 4; ks++) {
          int cl = clb + 2 * ks;
          bf16x8 vf = *(const bf16x8*)(vcur + r * 256 + ((cl ^ (r & 15)) << 4));
          union { uint32_t u[4]; bf16x8 v; } pb;
          pb.u[0] = W[ks >> 1][(ks & 1) * 4 + 0];
          pb.u[1] = W[ks >> 1][(ks & 1) * 4 + 1];
          pb.u[2] = W[ks >> 1][(ks & 1) * 4 + 2];
          pb.u[3] = W[ks >> 1][(ks & 1) * 4 + 3];
          a = MFMA32(vf, pb.v, a);
        }
        acc[dt] = a;
      }
      __builtin_amdgcn_s_setprio(0);
    }
    __syncthreads();
    cur ^= 1;
  }
  {
    float inv = 1.0f / lr;
    int q = qw + l31;
    size_t base = ((size_t)(b * L_ + q) * H_ + hh) * D_;
#pragma unroll
    for (int dt = 0; dt < 4; dt++)
#pragma unroll
      for (int u = 0; u < 4; u++) {
        bf16x4 o;
#pragma unroll
        for (int e = 0; e < 4; e++) o[e] = (bf16)(acc[dt][4 * u + e] * inv);
        *(bf16x4*)(attnout + base + dt * 32 + 8 * u + 4 * h) = o;
      }
  }
}

extern "C" void kernel_launch(void* const* d_in, const int* in_sizes, int n_in,
                              void* d_out, int out_size, void* d_ws, size_t ws_size,
                              hipStream_t stream) {
  const float* x = (const float*)d_in[0];
  const float* wq = (const float*)d_in[1];
  const float* wk = (const float*)d_in[2];
  const float* wv = (const float*)d_in[3];
  const float* wo = (const float*)d_in[4];
  const float* bq = (const float*)d_in[5];
  const float* bk = (const float*)d_in[6];
  const float* bv = (const float*)d_in[7];
  const float* k_cache = (const float*)d_in[8];
  const float* v_cache = (const float*)d_in[9];
  const int* offp = (const int*)d_in[10];

  char* w = (char*)d_ws;
  size_t off = 0;
  auto alloc = [&](size_t bytes) -> char* {
    char* p = w + off;
    off += (bytes + 255) & ~(size_t)255;
    return p;
  };
  const size_t nBLE = (size_t)B_ * L_ * E_;
  const size_t nBLKV = (size_t)B_ * L_ * EKV_;
  const size_t nKV = (size_t)B_ * HKV_ * S_ * D_;
  const size_t nBHLD = (size_t)B_ * H_ * L_ * D_;  // 8388608
  bf16* xb = (bf16*)alloc(nBLE * 2);
  bf16* wqb = (bf16*)alloc((size_t)E_ * E_ * 2);
  bf16* wkb = (bf16*)alloc((size_t)EKV_ * E_ * 2);
  bf16* wvb = (bf16*)alloc((size_t)EKV_ * E_ * 2);
  bf16* wob = (bf16*)alloc((size_t)E_ * E_ * 2);
  bf16* q_lin = (bf16*)alloc(nBLE * 2);
  bf16* k_lin = (bf16*)alloc(nBLKV * 2);
  bf16* v_lin = (bf16*)alloc(nBLKV * 2);
  bf16* qbuf = (bf16*)alloc(nBLE * 2);
  bf16* k_all = (bf16*)alloc(nKV * 2);
  bf16* vtall = (bf16*)alloc(nKV * 2);
  bf16* attnout = (bf16*)alloc(nBLE * 2);
  float2* trig = (float2*)alloc((size_t)L_ * 64 * sizeof(float2));
  // split-K partials (guarded by ws_size)
  float* part_o = (float*)alloc(2 * nBHLD * sizeof(float));
  float* part_ml = (float*)alloc(2 * (size_t)B_ * H_ * L_ * 2 * sizeof(float));
  const bool use_split = (off <= ws_size);

  cvt_kernel<<<(int)(nBLE / 1024), 256, 0, stream>>>(x, xb, (int)nBLE);
  cvt_kernel<<<(int)((size_t)E_ * E_ / 1024), 256, 0, stream>>>(wq, wqb, E_ * E_);
  cvt_kernel<<<(int)((size_t)EKV_ * E_ / 1024), 256, 0, stream>>>(wk, wkb, EKV_ * E_);
  cvt_kernel<<<(int)((size_t)EKV_ * E_ / 1024), 256, 0, stream>>>(wv, wvb, EKV_ * E_);
  cvt_kernel<<<(int)((size_t)E_ * E_ / 1024), 256, 0, stream>>>(wo, wob, E_ * E_);
  trig_kernel<<<L_, 64, 0, stream>>>(offp, trig);

  const int M = B_ * L_;  // 4096
  gemm_nt<0><<<dim3(M / 128, E_ / 128), 256, 0, stream>>>(xb, wqb, bq, q_lin, M, E_, E_);
  gemm_nt<0><<<dim3(M / 128, EKV_ / 128), 256, 0, stream>>>(xb, wkb, bk, k_lin, M, EKV_, E_);
  gemm_nt<0><<<dim3(M / 128, EKV_ / 128), 256, 0, stream>>>(xb, wvb, bv, v_lin, M, EKV_, E_);
  rope_q_kernel<<<B_ * L_ / 2, 256, 0, stream>>>(q_lin, trig, qbuf);
  build_k_kernel<<<dim3(S_, B_ * HKV_), 128, 0, stream>>>(k_cache, k_lin, trig, k_all);
  build_vt_kernel<<<dim3(S_ / 64, D_ / 64, B_ * HKV_), 256, 0, stream>>>(v_cache, v_lin, vtall);
  if (use_split) {
    attn_split_kernel<<<dim3(16, 32, 2), 256, 0, stream>>>(qbuf, k_all, vtall, part_o, part_ml);
    attn_merge_kernel<<<(int)(nBHLD / 4 / 256), 256, 0, stream>>>(part_o, part_ml, attnout);
  } else {
    attn_kernel<<<dim3(16, 32), 256, 0, stream>>>(qbuf, k_all, vtall, attnout);
  }
  gemm_nt<1><<<dim3(M / 128, E_ / 128), 256, 0, stream>>>(attnout, wob, nullptr, d_out, M, E_, E_);
}

// Round 11
// 346.901 us; speedup vs baseline: 1.2040x; 1.2040x over previous
//
#include <hip/hip_runtime.h>
#include <hip/hip_bf16.h>
#include <stdint.h>

typedef __bf16 bf16;
typedef __bf16 bf16x8 __attribute__((ext_vector_type(8)));
typedef __bf16 bf16x4 __attribute__((ext_vector_type(4)));
typedef float f32x4 __attribute__((ext_vector_type(4)));
typedef float f32x16 __attribute__((ext_vector_type(16)));

#define B_ 2
#define L_ 2048
#define E_ 2048
#define H_ 16
#define HKV_ 2
#define G_ 8
#define D_ 128
#define SPAST_ 2048
#define S_ 4096
#define EKV_ 256

#define MFMA16(a, b, c) __builtin_amdgcn_mfma_f32_16x16x32_bf16(a, b, c, 0, 0, 0)
#define MFMA32(a, b, c) __builtin_amdgcn_mfma_f32_32x32x16_bf16(a, b, c, 0, 0, 0)

__device__ __forceinline__ void gload16(const bf16* g, bf16* l) {
  __builtin_amdgcn_global_load_lds(
      (__attribute__((address_space(1))) void*)g,
      (__attribute__((address_space(3))) void*)l, 16, 0, 0);
}

// ---------------- f32 -> bf16 conversion ----------------
__global__ void cvt_kernel(const float* __restrict__ src, bf16* __restrict__ dst, int n) {
  int i = (blockIdx.x * 256 + threadIdx.x) * 4;
  if (i >= n) return;
  float4 v = *(const float4*)(src + i);
  bf16x4 o;
  o[0] = (bf16)v.x; o[1] = (bf16)v.y; o[2] = (bf16)v.z; o[3] = (bf16)v.w;
  *(bf16x4*)(dst + i) = o;
}

// ---------------- trig table ----------------
__global__ void trig_kernel(const int* __restrict__ offp, float2* __restrict__ trig) {
  int l = blockIdx.x, j = threadIdx.x;  // 64 threads
  float inv = exp2f(-(float)j * (13.287712379549449f / 64.0f));  // log2(10000)
  float ang = (float)(*offp + l) * inv;
  trig[l * 64 + j] = make_float2(cosf(ang), sinf(ang));
}

// ---------------- NT GEMM: C(M,N) = A(M,K) @ Bw(N,K)^T + bias (2-phase dbuf) ----------------
template <int OUTF32>
__global__ __launch_bounds__(256) void gemm_nt(const bf16* __restrict__ A,
                                               const bf16* __restrict__ Bw,
                                               const float* __restrict__ bias,
                                               void* __restrict__ Cout,
                                               int M, int N, int K) {
  __shared__ bf16 As[2 * 128 * 64];
  __shared__ bf16 Bs[2 * 128 * 64];
  const int tid = threadIdx.x;
  const int wid = tid >> 6, lane = tid & 63;
  const int ln15 = lane & 15, lq = lane >> 4;
  const int row0 = blockIdx.x * 128, col0 = blockIdx.y * 128;
  const int wr = wid >> 1, wc = wid & 1;
  f32x4 acc[4][4] = {};
  char* AsB = (char*)As;
  char* BsB = (char*)Bs;

  auto STAGE = [&](int buf, int k0) {
    char* ad = AsB + buf * 16384;
    char* bd = BsB + buf * 16384;
#pragma unroll
    for (int j = 0; j < 4; j++) {
      int cid = j * 256 + tid;
      int r = cid >> 3, c = cid & 7;
      int csw = (c ^ (r & 7)) << 3;
      gload16(A + (size_t)(row0 + r) * K + k0 + csw, (bf16*)(ad + (j * 256 + wid * 64) * 16));
      gload16(Bw + (size_t)(col0 + r) * K + k0 + csw, (bf16*)(bd + (j * 256 + wid * 64) * 16));
    }
  };

  STAGE(0, 0);
  __syncthreads();
  int cur = 0;
  for (int k0 = 0; k0 < K; k0 += 64) {
    if (k0 + 64 < K) STAGE(cur ^ 1, k0 + 64);
    char* ac = AsB + cur * 16384;
    char* bc = BsB + cur * 16384;
    bf16x8 af[4][2], bfm[4][2];
#pragma unroll
    for (int m = 0; m < 4; m++) {
#pragma unroll
      for (int kk = 0; kk < 2; kk++) {
        int Ra = wr * 64 + m * 16 + ln15;
        int Rb = wc * 64 + m * 16 + ln15;
        int c = (kk << 2) + lq;
        af[m][kk] = *(const bf16x8*)(ac + Ra * 128 + ((c ^ (Ra & 7)) << 4));
        bfm[m][kk] = *(const bf16x8*)(bc + Rb * 128 + ((c ^ (Rb & 7)) << 4));
      }
    }
    __builtin_amdgcn_s_setprio(1);
#pragma unroll
    for (int m = 0; m < 4; m++)
#pragma unroll
      for (int n = 0; n < 4; n++)
#pragma unroll
        for (int kk = 0; kk < 2; kk++)
          acc[m][n] = MFMA16(af[m][kk], bfm[n][kk], acc[m][n]);
    __builtin_amdgcn_s_setprio(0);
    __syncthreads();
    cur ^= 1;
  }
#pragma unroll
  for (int m = 0; m < 4; m++) {
    int gr0 = row0 + wr * 64 + m * 16 + 4 * lq;
#pragma unroll
    for (int n = 0; n < 4; n++) {
      int gc = col0 + wc * 64 + n * 16 + ln15;
      float bv = bias ? bias[gc] : 0.0f;
#pragma unroll
      for (int reg = 0; reg < 4; reg++) {
        float v = acc[m][n][reg] + bv;
        size_t idx = (size_t)(gr0 + reg) * N + gc;
        if (OUTF32)
          ((float*)Cout)[idx] = v;
        else
          ((bf16*)Cout)[idx] = (bf16)v;
      }
    }
  }
}

// ---------------- RoPE on Q (vectorized bf16x8), fold softmax scale*log2e ----------------
__global__ void rope_q_kernel(const bf16* __restrict__ q_lin, const float2* __restrict__ trig,
                              bf16* __restrict__ qbuf) {
  int bl = blockIdx.x * 2 + (threadIdx.x >> 7);  // grid = B*L/2
  int b = bl >> 11, l = bl & 2047;
  int u = threadIdx.x & 127;
  int h = u >> 3, j0 = (u & 7) * 8;
  const float QS = 0.08838834764831845f * 1.4426950408889634f;  // 1/sqrt(128) * log2(e)
  const bf16* src = q_lin + (size_t)bl * E_ + h * D_ + j0;
  bf16x8 x1 = *(const bf16x8*)(src);
  bf16x8 x2 = *(const bf16x8*)(src + 64);
  bf16x8 o1, o2;
#pragma unroll
  for (int e = 0; e < 8; e++) {
    float2 cs = trig[l * 64 + j0 + e];
    float a = (float)x1[e], c = (float)x2[e];
    o1[e] = (bf16)((a * cs.x - c * cs.y) * QS);
    o2[e] = (bf16)((c * cs.x + a * cs.y) * QS);
  }
  size_t o = ((size_t)(b * H_ + h) * L_ + l) * D_ + j0;
  *(bf16x8*)(qbuf + o) = o1;
  *(bf16x8*)(qbuf + o + 64) = o2;
}

// ---------------- build k_all (B,HKV,S,D) ----------------
__global__ void build_k_kernel(const float* __restrict__ k_cache, const bf16* __restrict__ k_lin,
                               const float2* __restrict__ trig, bf16* __restrict__ k_all) {
  int d = threadIdx.x;  // 128
  int s = blockIdx.x;
  int bz = blockIdx.y;  // b*HKV + hkv
  size_t oidx = ((size_t)bz * S_ + s) * D_ + d;
  if (s < SPAST_) {
    k_all[oidx] = (bf16)k_cache[((size_t)bz * SPAST_ + s) * D_ + d];
  } else {
    int l = s - SPAST_;
    int b = bz >> 1, kh = bz & 1;
    int j = d & 63;
    float2 cs = trig[l * 64 + j];
    size_t base = (size_t)(b * L_ + l) * EKV_ + kh * D_;
    float x1 = (float)k_lin[base + j];
    float x2 = (float)k_lin[base + 64 + j];
    float v = (d < 64) ? (x1 * cs.x - x2 * cs.y) : (x2 * cs.x + x1 * cs.y);
    k_all[oidx] = (bf16)v;
  }
}

// ---------------- build transposed V: vtall (B,HKV,D,S) (vectorized) ----------------
__global__ void build_vt_kernel(const float* __restrict__ v_cache, const bf16* __restrict__ v_lin,
                                bf16* __restrict__ vtall) {
  __shared__ float tile[64][68];
  int s0 = blockIdx.x * 64;
  int d0 = blockIdx.y * 64;
  int bz = blockIdx.z;
  int b = bz >> 1, kh = bz & 1;
#pragma unroll
  for (int it = 0; it < 4; it++) {
    int idx = it * 256 + threadIdx.x;  // 0..1023
    int ss = idx >> 4, dd0 = (idx & 15) * 4;
    int s = s0 + ss;
    float4 v;
    if (s < SPAST_) {
      v = *(const float4*)(v_cache + ((size_t)bz * SPAST_ + s) * D_ + d0 + dd0);
    } else {
      bf16x4 t = *(const bf16x4*)(v_lin + (size_t)(b * L_ + (s - SPAST_)) * EKV_ + kh * D_ + d0 + dd0);
      v = make_float4((float)t[0], (float)t[1], (float)t[2], (float)t[3]);
    }
    tile[ss][dd0] = v.x; tile[ss][dd0 + 1] = v.y;
    tile[ss][dd0 + 2] = v.z; tile[ss][dd0 + 3] = v.w;
  }
  __syncthreads();
#pragma unroll
  for (int it = 0; it < 4; it++) {
    int idx = it * 256 + threadIdx.x;
    int dd = idx >> 4, ss0 = (idx & 15) * 4;
    bf16x4 o;
#pragma unroll
    for (int e = 0; e < 4; e++) o[e] = (bf16)tile[ss0 + e][dd];
    *(bf16x4*)(vtall + ((size_t)bz * D_ + d0 + dd) * S_ + s0 + ss0) = o;
  }
}

// ---------------- flash attention, split-K-across-blocks variant ----------------
// grid (16, 32, 2) x 256 threads. z selects key half; each block runs the proven R6 loop over
// 32-key chunks (LDS 32KB). launch_bounds(256,2): weak reg cap -- natural ~90-104 VGPR lands in
// the <=128 tier = 4 waves/SIMD. ((256,4)/(512,4) pinned the 64-reg tier and spilled: R7, R10.)
// Writes f32 partials (O, m, l); attn_merge_kernel combines.
__global__ __launch_bounds__(256, 2) void attn_split_kernel(const bf16* __restrict__ qbuf,
                                                            const bf16* __restrict__ k_all,
                                                            const bf16* __restrict__ vtall,
                                                            float* __restrict__ part_o,
                                                            float* __restrict__ part_ml) {
  __shared__ bf16 Ks[2 * 32 * 128];  // [key][d] 256B rows, swizzled 16B slots (8KB/buf)
  __shared__ bf16 Vs[2 * 32 * 128];  // row r = d-quad {4r..4r+3} x 32 keys (8KB/buf)
  const int tid = threadIdx.x;
  const int wid = tid >> 6, lane = tid & 63;
  const int l31 = lane & 31, h = lane >> 5;
  const int xq = ((blockIdx.y >> 4) & 1) ? (15 - (int)blockIdx.x) : (int)blockIdx.x;
  const int q0 = xq * 128;
  const int bh = blockIdx.y;
  const int z = blockIdx.z;
  const int b = bh / H_, hh = bh % H_;
  const int hkv = hh / G_;
  const bf16* kb = k_all + (size_t)(b * HKV_ + hkv) * S_ * D_;
  const bf16* vb = vtall + (size_t)(b * HKV_ + hkv) * D_ * S_;
  const int qw = q0 + wid * 32;
  // staging: 512 K slots + 512 V slots per chunk over 256 threads (2+2 each)
  const int r0 = tid >> 4;                       // 0..15
  const int cl0 = (tid & 15) ^ (r0 & 15);        // logical 16B slot
  const bf16* krow = kb + r0 * D_ + cl0 * 8;
  const bf16* vrow = vb + (size_t)(4 * r0 + (cl0 >> 2)) * S_ + (cl0 & 3) * 8;
  const int dstoff = (wid * 64) * 16;
  // Q fragments (B operand): col=q=l31, k-dim d = ks*16 + 8h + i
  bf16x8 qf[8];
  {
    const bf16* qp = qbuf + ((size_t)(b * H_ + hh) * L_ + qw + l31) * D_ + h * 8;
#pragma unroll
    for (int ks = 0; ks < 8; ks++) qf[ks] = *(const bf16x8*)(qp + ks * 16);
  }
  f32x16 acc[4] = {};
  float mr = -3e38f, lr = 0.f;

  auto STAGE = [&](int buf, int s0) {
    char* kd = (char*)Ks + buf * 8192 + dstoff;
    char* vd = (char*)Vs + buf * 8192 + dstoff;
    size_t ko = (size_t)s0 << 7;  // s0 * D_
    gload16(krow + ko, (bf16*)(kd));
    gload16(krow + ko + 16 * D_, (bf16*)(kd + 4096));
    gload16(vrow + s0, (bf16*)(vd));
    gload16(vrow + s0 + (size_t)64 * S_, (bf16*)(vd + 4096));
  };

  const int nch2 = 2 * xq + 34;       // 32-key chunks per z ((4xq+68)/2)
  const int zb = z * nch2;
  const int smax_w = qw + 32 + SPAST_;

  STAGE(0, zb << 5);
  __syncthreads();
  int cur = 0;
  for (int i = 0; i < nch2; ++i) {
    int s0 = (zb + i) << 5;
    if (i + 1 < nch2) STAGE(cur ^ 1, s0 + 32);  // prefetch own next chunk
    if (s0 < smax_w) {
      char* kcur = (char*)Ks + cur * 8192;
      char* vcur = (char*)Vs + cur * 8192;
      // ---- swapped QK^T: lane holds q=l31, keys s0 + (r&3)+8*(r>>2)+4h
      f32x16 st;
      {
        f32x16 a = {};
        __builtin_amdgcn_s_setprio(1);
#pragma unroll
        for (int ks = 0; ks < 8; ks++) {
          int cl = 2 * ks + h;
          bf16x8 kf = *(const bf16x8*)(kcur + l31 * 256 + ((cl ^ (l31 & 15)) << 4));
          a = MFMA32(kf, qf[ks], a);
        }
        __builtin_amdgcn_s_setprio(0);
        st = a;
      }
      // ---- causal mask (z=1 diagonal chunks only)
      if (s0 + 31 > qw + SPAST_) {
        int q = qw + l31;
#pragma unroll
        for (int r = 0; r < 16; r++) {
          int key = s0 + (r & 3) + 8 * (r >> 2) + 4 * h;
          if (key > q + SPAST_) st[r] = -1e30f;
        }
      }
      // ---- online softmax: in-lane tree + 1 half-swap
      float mt = fmaxf(st[0], st[1]);
#pragma unroll
      for (int r = 2; r < 16; r++) mt = fmaxf(mt, st[r]);
      mt = fmaxf(mt, __shfl_xor(mt, 32));
      if (__any(mt - mr > 8.0f)) {  // T13 defer-max
        float mn = fmaxf(mr, mt);
        float fac = exp2f(mr - mn);
        mr = mn;
        lr *= fac;
#pragma unroll
        for (int dt = 0; dt < 4; dt++) acc[dt] *= fac;
      }
      float s = 0.f;
#pragma unroll
      for (int r = 0; r < 16; r++) {
        float p = exp2f(st[r] - mr);
        st[r] = p;
        s += p;
      }
      s += __shfl_xor(s, 32);
      lr += s;
      // ---- P -> bf16 dwords + permlane32_swap (VDST.hi <-> VSRC.lo)
      uint32_t W[8];
#pragma unroll
      for (int j = 0; j < 8; j++)
        asm("v_cvt_pk_bf16_f32 %0, %1, %2" : "=v"(W[j]) : "v"(st[2 * j]), "v"(st[2 * j + 1]));
#pragma unroll
      for (int s4 = 0; s4 < 8; s4 += 4) {
        asm volatile("v_permlane32_swap_b32 %0, %1" : "+v"(W[s4 + 0]), "+v"(W[s4 + 2]));
        asm volatile("v_permlane32_swap_b32 %0, %1" : "+v"(W[s4 + 1]), "+v"(W[s4 + 3]));
      }
      // ---- PV: O^T = V^T x P^T
      __builtin_amdgcn_s_setprio(1);
#pragma unroll
      for (int dt = 0; dt < 4; dt++) {
        int r = dt * 8 + (l31 >> 2);
        int clb = 4 * (l31 & 3) + h;
        f32x16 a = acc[dt];
#pragma unroll
        for (int ks = 0; ks < 2; ks++) {
          int cl = clb + 2 * ks;
          bf16x8 vf = *(const bf16x8*)(vcur + r * 256 + ((cl ^ (r & 15)) << 4));
          union { uint32_t u[4]; bf16x8 v; } pb;
          pb.u[0] = W[ks * 4 + 0];
          pb.u[1] = W[ks * 4 + 1];
          pb.u[2] = W[ks * 4 + 2];
          pb.u[3] = W[ks * 4 + 3];
          a = MFMA32(vf, pb.v, a);
        }
        acc[dt] = a;
      }
      __builtin_amdgcn_s_setprio(0);
    }
    __syncthreads();
    cur ^= 1;
  }
  // ---- partial epilogue: O unnormalized f32 + (m,l); layout [z][bh][L][D]
  {
    int q = qw + l31;
    float* po = part_o + (((size_t)z * 32 + bh) * L_ + q) * D_;
#pragma unroll
    for (int dt = 0; dt < 4; dt++) {
      union { f32x16 v; f32x4 q4[4]; } u;
      u.v = acc[dt];
#pragma unroll
      for (int uu = 0; uu < 4; uu++)
        *(f32x4*)(po + dt * 32 + 8 * uu + 4 * h) = u.q4[uu];
    }
    if (h == 0) {
      float* pm = part_ml + (((size_t)z * 32 + bh) * L_ + q) * 2;
      pm[0] = mr;
      pm[1] = lr;
    }
  }
}

// ---------------- merge the two key-half partials ----------------
__global__ __launch_bounds__(256) void attn_merge_kernel(const float* __restrict__ part_o,
                                                         const float* __restrict__ part_ml,
                                                         bf16* __restrict__ attnout) {
  int gid = blockIdx.x * 256 + threadIdx.x;  // over B*H*L*(D/4) = 2,097,152
  int d4 = (gid & 31) * 4;
  int rest = gid >> 5;
  int q = rest & (L_ - 1);
  int bh = rest >> 11;  // 0..31
  size_t qi = (size_t)bh * L_ + q;
  const float* m0p = part_ml + qi * 2;
  const float* m1p = part_ml + ((size_t)32 * L_ + qi) * 2;
  float m0 = m0p[0], l0 = m0p[1], m1 = m1p[0], l1 = m1p[1];
  float m = fmaxf(m0, m1);
  float f0 = exp2f(m0 - m), f1 = exp2f(m1 - m);
  float linv = 1.0f / (l0 * f0 + l1 * f1);
  f32x4 o0 = *(const f32x4*)(part_o + qi * D_ + d4);
  f32x4 o1 = *(const f32x4*)(part_o + (size_t)32 * L_ * D_ + qi * D_ + d4);
  int b = bh >> 4, h = bh & 15;
  bf16x4 o;
#pragma unroll
  for (int e = 0; e < 4; e++) o[e] = (bf16)((o0[e] * f0 + o1[e] * f1) * linv);
  *(bf16x4*)(attnout + ((size_t)(b * L_ + q) * H_ + h) * D_ + d4) = o;
}

// ---------------- fallback: round-9 attn kernel (no split; used when ws is too small) ----------------
__global__ __launch_bounds__(256, 2) void attn_kernel(const bf16* __restrict__ qbuf,
                                                      const bf16* __restrict__ k_all,
                                                      const bf16* __restrict__ vtall,
                                                      bf16* __restrict__ attnout) {
  __shared__ bf16 Ks[2 * 64 * 128];
  __shared__ bf16 Vs[2 * 64 * 128];
  const int tid = threadIdx.x;
  const int wid = tid >> 6, lane = tid & 63;
  const int l31 = lane & 31, h = lane >> 5;
  const int xq = ((blockIdx.y >> 4) & 1) ? (15 - (int)blockIdx.x) : (int)blockIdx.x;
  const int q0 = xq * 128;
  const int bh = blockIdx.y;
  const int b = bh / H_, hh = bh % H_;
  const int hkv = hh / G_;
  const bf16* kb = k_all + (size_t)(b * HKV_ + hkv) * S_ * D_;
  const bf16* vb = vtall + (size_t)(b * HKV_ + hkv) * D_ * S_;
  const int qw = q0 + wid * 32;
  bf16x8 qf[8];
  {
    const bf16* qp = qbuf + ((size_t)(b * H_ + hh) * L_ + qw + l31) * D_ + h * 8;
#pragma unroll
    for (int ks = 0; ks < 8; ks++) qf[ks] = *(const bf16x8*)(qp + ks * 16);
  }
  f32x16 acc[4] = {};
  float mr = -3e38f, lr = 0.f;

  auto STAGE = [&](int buf, int s0) {
    char* kd = (char*)Ks + buf * 16384;
    char* vd = (char*)Vs + buf * 16384;
#pragma unroll
    for (int j = 0; j < 4; j++) {
      int cid = j * 256 + tid;
      int r = cid >> 4;
      int cl = (cid & 15) ^ (r & 15);
      gload16(kb + (size_t)(s0 + r) * D_ + cl * 8, (bf16*)(kd + (j * 256 + wid * 64) * 16));
      gload16(vb + (size_t)(2 * r + (cl >> 3)) * S_ + s0 + (cl & 7) * 8,
              (bf16*)(vd + (j * 256 + wid * 64) * 16));
    }
  };

  const int nchunk = (q0 + 128 + SPAST_) >> 6;
  const int smax_w = qw + 32 + SPAST_;

  STAGE(0, 0);
  __syncthreads();
  int cur = 0;
  for (int sc = 0; sc < nchunk; ++sc) {
    int s0 = sc << 6;
    if (sc + 1 < nchunk) STAGE(cur ^ 1, s0 + 64);
    if (s0 < smax_w) {
      char* kcur = (char*)Ks + cur * 16384;
      char* vcur = (char*)Vs + cur * 16384;
      f32x16 st[2];
      __builtin_amdgcn_s_setprio(1);
#pragma unroll
      for (int t = 0; t < 2; t++) {
        f32x16 a = {};
        int R = t * 32 + l31;
#pragma unroll
        for (int ks = 0; ks < 8; ks++) {
          int cl = 2 * ks + h;
          bf16x8 kf = *(const bf16x8*)(kcur + R * 256 + ((cl ^ (R & 15)) << 4));
          a = MFMA32(kf, qf[ks], a);
        }
        st[t] = a;
      }
      __builtin_amdgcn_s_setprio(0);
      if (s0 + 63 > qw + SPAST_) {
        int q = qw + l31;
#pragma unroll
        for (int t = 0; t < 2; t++)
#pragma unroll
          for (int r = 0; r < 16; r++) {
            int key = s0 + t * 32 + (r & 3) + 8 * (r >> 2) + 4 * h;
            if (key > q + SPAST_) st[t][r] = -1e30f;
          }
      }
      float mt = fmaxf(st[0][0], st[0][1]);
#pragma unroll
      for (int r = 2; r < 16; r++) mt = fmaxf(mt, st[0][r]);
#pragma unroll
      for (int r = 0; r < 16; r++) mt = fmaxf(mt, st[1][r]);
      mt = fmaxf(mt, __shfl_xor(mt, 32));
      if (__any(mt - mr > 8.0f)) {
        float mn = fmaxf(mr, mt);
        float fac = exp2f(mr - mn);
        mr = mn;
        lr *= fac;
#pragma unroll
        for (int dt = 0; dt < 4; dt++) acc[dt] *= fac;
      }
      float s = 0.f;
#pragma unroll
      for (int t = 0; t < 2; t++)
#pragma unroll
        for (int r = 0; r < 16; r++) {
          float p = exp2f(st[t][r] - mr);
          st[t][r] = p;
          s += p;
        }
      s += __shfl_xor(s, 32);
      lr += s;
      uint32_t W[2][8];
#pragma unroll
      for (int t = 0; t < 2; t++)
#pragma unroll
        for (int j = 0; j < 8; j++)
          asm("v_cvt_pk_bf16_f32 %0, %1, %2"
              : "=v"(W[t][j])
              : "v"(st[t][2 * j]), "v"(st[t][2 * j + 1]));
#pragma unroll
      for (int t = 0; t < 2; t++)
#pragma unroll
        for (int s4 = 0; s4 < 8; s4 += 4) {
          asm volatile("v_permlane32_swap_b32 %0, %1" : "+v"(W[t][s4 + 0]), "+v"(W[t][s4 + 2]));
          asm volatile("v_permlane32_swap_b32 %0, %1" : "+v"(W[t][s4 + 1]), "+v"(W[t][s4 + 3]));
        }
      __builtin_amdgcn_s_setprio(1);
#pragma unroll
      for (int dt = 0; dt < 4; dt++) {
        int r = dt * 16 + (l31 >> 1);
        int clb = 8 * (l31 & 1) + h;
        f32x16 a = acc[dt];
#pragma unroll
        for (int ks = 0; ks < 4; ks++) {
          int cl = clb + 2 * ks;
          bf16x8 vf = *(const bf16x8*)(vcur + r * 256 + ((cl ^ (r & 15)) << 4));
          union { uint32_t u[4]; bf16x8 v; } pb;
          pb.u[0] = W[ks >> 1][(ks & 1) * 4 + 0];
          pb.u[1] = W[ks >> 1][(ks & 1) * 4 + 1];
          pb.u[2] = W[ks >> 1][(ks & 1) * 4 + 2];
          pb.u[3] = W[ks >> 1][(ks & 1) * 4 + 3];
          a = MFMA32(vf, pb.v, a);
        }
        acc[dt] = a;
      }
      __builtin_amdgcn_s_setprio(0);
    }
    __syncthreads();
    cur ^= 1;
  }
  {
    float inv = 1.0f / lr;
    int q = qw + l31;
    size_t base = ((size_t)(b * L_ + q) * H_ + hh) * D_;
#pragma unroll
    for (int dt = 0; dt < 4; dt++)
#pragma unroll
      for (int u = 0; u < 4; u++) {
        bf16x4 o;
#pragma unroll
        for (int e = 0; e < 4; e++) o[e] = (bf16)(acc[dt][4 * u + e] * inv);
        *(bf16x4*)(attnout + base + dt * 32 + 8 * u + 4 * h) = o;
      }
  }
}

extern "C" void kernel_launch(void* const* d_in, const int* in_sizes, int n_in,
                              void* d_out, int out_size, void* d_ws, size_t ws_size,
                              hipStream_t stream) {
  const float* x = (const float*)d_in[0];
  const float* wq = (const float*)d_in[1];
  const float* wk = (const float*)d_in[2];
  const float* wv = (const float*)d_in[3];
  const float* wo = (const float*)d_in[4];
  const float* bq = (const float*)d_in[5];
  const float* bk = (const float*)d_in[6];
  const float* bv = (const float*)d_in[7];
  const float* k_cache = (const float*)d_in[8];
  const float* v_cache = (const float*)d_in[9];
  const int* offp = (const int*)d_in[10];

  char* w = (char*)d_ws;
  size_t off = 0;
  auto alloc = [&](size_t bytes) -> char* {
    char* p = w + off;
    off += (bytes + 255) & ~(size_t)255;
    return p;
  };
  const size_t nBLE = (size_t)B_ * L_ * E_;
  const size_t nBLKV = (size_t)B_ * L_ * EKV_;
  const size_t nKV = (size_t)B_ * HKV_ * S_ * D_;
  const size_t nBHLD = (size_t)B_ * H_ * L_ * D_;  // 8388608
  bf16* xb = (bf16*)alloc(nBLE * 2);
  bf16* wqb = (bf16*)alloc((size_t)E_ * E_ * 2);
  bf16* wkb = (bf16*)alloc((size_t)EKV_ * E_ * 2);
  bf16* wvb = (bf16*)alloc((size_t)EKV_ * E_ * 2);
  bf16* wob = (bf16*)alloc((size_t)E_ * E_ * 2);
  bf16* q_lin = (bf16*)alloc(nBLE * 2);
  bf16* k_lin = (bf16*)alloc(nBLKV * 2);
  bf16* v_lin = (bf16*)alloc(nBLKV * 2);
  bf16* qbuf = (bf16*)alloc(nBLE * 2);
  bf16* k_all = (bf16*)alloc(nKV * 2);
  bf16* vtall = (bf16*)alloc(nKV * 2);
  bf16* attnout = (bf16*)alloc(nBLE * 2);
  float2* trig = (float2*)alloc((size_t)L_ * 64 * sizeof(float2));
  // split-K partials (guarded by ws_size)
  float* part_o = (float*)alloc(2 * nBHLD * sizeof(float));
  float* part_ml = (float*)alloc(2 * (size_t)B_ * H_ * L_ * 2 * sizeof(float));
  const bool use_split = (off <= ws_size);

  cvt_kernel<<<(int)(nBLE / 1024), 256, 0, stream>>>(x, xb, (int)nBLE);
  cvt_kernel<<<(int)((size_t)E_ * E_ / 1024), 256, 0, stream>>>(wq, wqb, E_ * E_);
  cvt_kernel<<<(int)((size_t)EKV_ * E_ / 1024), 256, 0, stream>>>(wk, wkb, EKV_ * E_);
  cvt_kernel<<<(int)((size_t)EKV_ * E_ / 1024), 256, 0, stream>>>(wv, wvb, EKV_ * E_);
  cvt_kernel<<<(int)((size_t)E_ * E_ / 1024), 256, 0, stream>>>(wo, wob, E_ * E_);
  trig_kernel<<<L_, 64, 0, stream>>>(offp, trig);

  const int M = B_ * L_;  // 4096
  gemm_nt<0><<<dim3(M / 128, E_ / 128), 256, 0, stream>>>(xb, wqb, bq, q_lin, M, E_, E_);
  gemm_nt<0><<<dim3(M / 128, EKV_ / 128), 256, 0, stream>>>(xb, wkb, bk, k_lin, M, EKV_, E_);
  gemm_nt<0><<<dim3(M / 128, EKV_ / 128), 256, 0, stream>>>(xb, wvb, bv, v_lin, M, EKV_, E_);
  rope_q_kernel<<<B_ * L_ / 2, 256, 0, stream>>>(q_lin, trig, qbuf);
  build_k_kernel<<<dim3(S_, B_ * HKV_), 128, 0, stream>>>(k_cache, k_lin, trig, k_all);
  build_vt_kernel<<<dim3(S_ / 64, D_ / 64, B_ * HKV_), 256, 0, stream>>>(v_cache, v_lin, vtall);
  if (use_split) {
    attn_split_kernel<<<dim3(16, 32, 2), 256, 0, stream>>>(qbuf, k_all, vtall, part_o, part_ml);
    attn_merge_kernel<<<(int)(nBHLD / 4 / 256), 256, 0, stream>>>(part_o, part_ml, attnout);
  } else {
    attn_kernel<<<dim3(16, 32), 256, 0, stream>>>(qbuf, k_all, vtall, attnout);
  }
  gemm_nt<1><<<dim3(M / 128, E_ / 128), 256, 0, stream>>>(attnout, wob, nullptr, d_out, M, E_, E_);
}

// Round 12
// 344.901 us; speedup vs baseline: 1.2110x; 1.0058x over previous
//
#include <hip/hip_runtime.h>
#include <hip/hip_bf16.h>
#include <stdint.h>

typedef __bf16 bf16;
typedef __bf16 bf16x8 __attribute__((ext_vector_type(8)));
typedef __bf16 bf16x4 __attribute__((ext_vector_type(4)));
typedef float f32x4 __attribute__((ext_vector_type(4)));
typedef float f32x16 __attribute__((ext_vector_type(16)));

#define B_ 2
#define L_ 2048
#define E_ 2048
#define H_ 16
#define HKV_ 2
#define G_ 8
#define D_ 128
#define SPAST_ 2048
#define S_ 4096
#define EKV_ 256

#define MFMA16(a, b, c) __builtin_amdgcn_mfma_f32_16x16x32_bf16(a, b, c, 0, 0, 0)
#define MFMA32(a, b, c) __builtin_amdgcn_mfma_f32_32x32x16_bf16(a, b, c, 0, 0, 0)

__device__ __forceinline__ void gload16(const bf16* g, bf16* l) {
  __builtin_amdgcn_global_load_lds(
      (__attribute__((address_space(1))) void*)g,
      (__attribute__((address_space(3))) void*)l, 16, 0, 0);
}

// ---------------- f32 -> bf16 conversion ----------------
__global__ void cvt_kernel(const float* __restrict__ src, bf16* __restrict__ dst, int n) {
  int i = (blockIdx.x * 256 + threadIdx.x) * 4;
  if (i >= n) return;
  float4 v = *(const float4*)(src + i);
  bf16x4 o;
  o[0] = (bf16)v.x; o[1] = (bf16)v.y; o[2] = (bf16)v.z; o[3] = (bf16)v.w;
  *(bf16x4*)(dst + i) = o;
}

// ---------------- trig table ----------------
__global__ void trig_kernel(const int* __restrict__ offp, float2* __restrict__ trig) {
  int l = blockIdx.x, j = threadIdx.x;  // 64 threads
  float inv = exp2f(-(float)j * (13.287712379549449f / 64.0f));  // log2(10000)
  float ang = (float)(*offp + l) * inv;
  trig[l * 64 + j] = make_float2(cosf(ang), sinf(ang));
}

// ---------------- NT GEMM: C(M,N) = A(M,K) @ Bw(N,K)^T + bias ----------------
// 128x128 tile, BK=64, 4 waves. T4 counted-vmcnt 2-phase: prefetch loads stay in
// flight across the barrier; vmcnt(8) waits only the PREVIOUS K-tile's 8 loads.
template <int OUTF32>
__global__ __launch_bounds__(256) void gemm_nt(const bf16* __restrict__ A,
                                               const bf16* __restrict__ Bw,
                                               const float* __restrict__ bias,
                                               void* __restrict__ Cout,
                                               int M, int N, int K) {
  __shared__ bf16 As[2 * 128 * 64];
  __shared__ bf16 Bs[2 * 128 * 64];
  const int tid = threadIdx.x;
  const int wid = tid >> 6, lane = tid & 63;
  const int ln15 = lane & 15, lq = lane >> 4;
  const int row0 = blockIdx.x * 128, col0 = blockIdx.y * 128;
  const int wr = wid >> 1, wc = wid & 1;
  f32x4 acc[4][4] = {};
  char* AsB = (char*)As;
  char* BsB = (char*)Bs;

  auto STAGE = [&](int buf, int k0) {  // 8 loads per thread
    char* ad = AsB + buf * 16384;
    char* bd = BsB + buf * 16384;
#pragma unroll
    for (int j = 0; j < 4; j++) {
      int cid = j * 256 + tid;
      int r = cid >> 3, c = cid & 7;
      int csw = (c ^ (r & 7)) << 3;
      gload16(A + (size_t)(row0 + r) * K + k0 + csw, (bf16*)(ad + (j * 256 + wid * 64) * 16));
      gload16(Bw + (size_t)(col0 + r) * K + k0 + csw, (bf16*)(bd + (j * 256 + wid * 64) * 16));
    }
  };

  STAGE(0, 0);
  int cur = 0;
  for (int k0 = 0; k0 < K; k0 += 64) {
    if (k0 + 64 < K) {
      STAGE(cur ^ 1, k0 + 64);                       // +8 in flight
      asm volatile("s_waitcnt vmcnt(8)" ::: "memory");  // cur's 8 done; next 8 fly on
    } else {
      asm volatile("s_waitcnt vmcnt(0)" ::: "memory");
    }
    __builtin_amdgcn_s_barrier();  // cur data visible to all waves
    char* ac = AsB + cur * 16384;
    char* bc = BsB + cur * 16384;
    bf16x8 af[4][2], bfm[4][2];
#pragma unroll
    for (int m = 0; m < 4; m++) {
#pragma unroll
      for (int kk = 0; kk < 2; kk++) {
        int Ra = wr * 64 + m * 16 + ln15;
        int Rb = wc * 64 + m * 16 + ln15;
        int c = (kk << 2) + lq;
        af[m][kk] = *(const bf16x8*)(ac + Ra * 128 + ((c ^ (Ra & 7)) << 4));
        bfm[m][kk] = *(const bf16x8*)(bc + Rb * 128 + ((c ^ (Rb & 7)) << 4));
      }
    }
    __builtin_amdgcn_s_setprio(1);
#pragma unroll
    for (int m = 0; m < 4; m++)
#pragma unroll
      for (int n = 0; n < 4; n++)
#pragma unroll
        for (int kk = 0; kk < 2; kk++)
          acc[m][n] = MFMA16(af[m][kk], bfm[n][kk], acc[m][n]);
    __builtin_amdgcn_s_setprio(0);
    __builtin_amdgcn_s_barrier();  // all waves done reading cur (next STAGE overwrites it)
    cur ^= 1;
  }
#pragma unroll
  for (int m = 0; m < 4; m++) {
    int gr0 = row0 + wr * 64 + m * 16 + 4 * lq;
#pragma unroll
    for (int n = 0; n < 4; n++) {
      int gc = col0 + wc * 64 + n * 16 + ln15;
      float bv = bias ? bias[gc] : 0.0f;
#pragma unroll
      for (int reg = 0; reg < 4; reg++) {
        float v = acc[m][n][reg] + bv;
        size_t idx = (size_t)(gr0 + reg) * N + gc;
        if (OUTF32)
          ((float*)Cout)[idx] = v;
        else
          ((bf16*)Cout)[idx] = (bf16)v;
      }
    }
  }
}

// ---------------- RoPE on Q (vectorized bf16x8), fold softmax scale*log2e ----------------
__global__ void rope_q_kernel(const bf16* __restrict__ q_lin, const float2* __restrict__ trig,
                              bf16* __restrict__ qbuf) {
  int bl = blockIdx.x * 2 + (threadIdx.x >> 7);  // grid = B*L/2
  int b = bl >> 11, l = bl & 2047;
  int u = threadIdx.x & 127;
  int h = u >> 3, j0 = (u & 7) * 8;
  const float QS = 0.08838834764831845f * 1.4426950408889634f;  // 1/sqrt(128) * log2(e)
  const bf16* src = q_lin + (size_t)bl * E_ + h * D_ + j0;
  bf16x8 x1 = *(const bf16x8*)(src);
  bf16x8 x2 = *(const bf16x8*)(src + 64);
  bf16x8 o1, o2;
#pragma unroll
  for (int e = 0; e < 8; e++) {
    float2 cs = trig[l * 64 + j0 + e];
    float a = (float)x1[e], c = (float)x2[e];
    o1[e] = (bf16)((a * cs.x - c * cs.y) * QS);
    o2[e] = (bf16)((c * cs.x + a * cs.y) * QS);
  }
  size_t o = ((size_t)(b * H_ + h) * L_ + l) * D_ + j0;
  *(bf16x8*)(qbuf + o) = o1;
  *(bf16x8*)(qbuf + o + 64) = o2;
}

// ---------------- build k_all (B,HKV,S,D) ----------------
__global__ void build_k_kernel(const float* __restrict__ k_cache, const bf16* __restrict__ k_lin,
                               const float2* __restrict__ trig, bf16* __restrict__ k_all) {
  int d = threadIdx.x;  // 128
  int s = blockIdx.x;
  int bz = blockIdx.y;  // b*HKV + hkv
  size_t oidx = ((size_t)bz * S_ + s) * D_ + d;
  if (s < SPAST_) {
    k_all[oidx] = (bf16)k_cache[((size_t)bz * SPAST_ + s) * D_ + d];
  } else {
    int l = s - SPAST_;
    int b = bz >> 1, kh = bz & 1;
    int j = d & 63;
    float2 cs = trig[l * 64 + j];
    size_t base = (size_t)(b * L_ + l) * EKV_ + kh * D_;
    float x1 = (float)k_lin[base + j];
    float x2 = (float)k_lin[base + 64 + j];
    float v = (d < 64) ? (x1 * cs.x - x2 * cs.y) : (x2 * cs.x + x1 * cs.y);
    k_all[oidx] = (bf16)v;
  }
}

// ---------------- build transposed V: vtall (B,HKV,D,S) (vectorized) ----------------
__global__ void build_vt_kernel(const float* __restrict__ v_cache, const bf16* __restrict__ v_lin,
                                bf16* __restrict__ vtall) {
  __shared__ float tile[64][68];
  int s0 = blockIdx.x * 64;
  int d0 = blockIdx.y * 64;
  int bz = blockIdx.z;
  int b = bz >> 1, kh = bz & 1;
#pragma unroll
  for (int it = 0; it < 4; it++) {
    int idx = it * 256 + threadIdx.x;  // 0..1023
    int ss = idx >> 4, dd0 = (idx & 15) * 4;
    int s = s0 + ss;
    float4 v;
    if (s < SPAST_) {
      v = *(const float4*)(v_cache + ((size_t)bz * SPAST_ + s) * D_ + d0 + dd0);
    } else {
      bf16x4 t = *(const bf16x4*)(v_lin + (size_t)(b * L_ + (s - SPAST_)) * EKV_ + kh * D_ + d0 + dd0);
      v = make_float4((float)t[0], (float)t[1], (float)t[2], (float)t[3]);
    }
    tile[ss][dd0] = v.x; tile[ss][dd0 + 1] = v.y;
    tile[ss][dd0 + 2] = v.z; tile[ss][dd0 + 3] = v.w;
  }
  __syncthreads();
#pragma unroll
  for (int it = 0; it < 4; it++) {
    int idx = it * 256 + threadIdx.x;
    int dd = idx >> 4, ss0 = (idx & 15) * 4;
    bf16x4 o;
#pragma unroll
    for (int e = 0; e < 4; e++) o[e] = (bf16)tile[ss0 + e][dd];
    *(bf16x4*)(vtall + ((size_t)bz * D_ + d0 + dd) * S_ + s0 + ss0) = o;
  }
}

// ---------------- flash attention (R6/R9 structure + T4 counted-vmcnt) ----------------
// grid (16, 32); 4 waves x 32 q-rows; 64-key chunks dbuf in LDS.
// Swapped QK^T (A=K,B=Q -> S^T); in-register P via cvt_pk + permlane32_swap (T12);
// 4-bit slot swizzle, conflict-free. NEW: counted vmcnt(8) + raw barriers -- the
// prefetch's 8 loads stay in flight across the barrier instead of being drained.
__global__ __launch_bounds__(256, 2) void attn_kernel(const bf16* __restrict__ qbuf,
                                                      const bf16* __restrict__ k_all,
                                                      const bf16* __restrict__ vtall,
                                                      bf16* __restrict__ attnout) {
  __shared__ bf16 Ks[2 * 64 * 128];   // [key][d], 256B rows, swizzled 16B slots
  __shared__ bf16 Vs[2 * 64 * 128];   // paired rows: row r = {d=2r | d=2r+1}, 256B
  const int tid = threadIdx.x;
  const int wid = tid >> 6, lane = tid & 63;
  const int l31 = lane & 31, h = lane >> 5;
  const int xq = ((blockIdx.y >> 4) & 1) ? (15 - (int)blockIdx.x) : (int)blockIdx.x;
  const int q0 = xq * 128;
  const int bh = blockIdx.y;
  const int b = bh / H_, hh = bh % H_;
  const int hkv = hh / G_;
  const bf16* kb = k_all + (size_t)(b * HKV_ + hkv) * S_ * D_;
  const bf16* vb = vtall + (size_t)(b * HKV_ + hkv) * D_ * S_;
  const int qw = q0 + wid * 32;
  bf16x8 qf[8];
  {
    const bf16* qp = qbuf + ((size_t)(b * H_ + hh) * L_ + qw + l31) * D_ + h * 8;
#pragma unroll
    for (int ks = 0; ks < 8; ks++) qf[ks] = *(const bf16x8*)(qp + ks * 16);
  }
  f32x16 acc[4] = {};
  float mr = -3e38f, lr = 0.f;

  auto STAGE = [&](int buf, int s0) {  // 8 loads per thread
    char* kd = (char*)Ks + buf * 16384;
    char* vd = (char*)Vs + buf * 16384;
#pragma unroll
    for (int j = 0; j < 4; j++) {
      int cid = j * 256 + tid;
      int r = cid >> 4;
      int cl = (cid & 15) ^ (r & 15);
      gload16(kb + (size_t)(s0 + r) * D_ + cl * 8, (bf16*)(kd + (j * 256 + wid * 64) * 16));
      gload16(vb + (size_t)(2 * r + (cl >> 3)) * S_ + s0 + (cl & 7) * 8,
              (bf16*)(vd + (j * 256 + wid * 64) * 16));
    }
  };

  const int nchunk = (q0 + 128 + SPAST_) >> 6;  // block-uniform
  const int smax_w = qw + 32 + SPAST_;

  STAGE(0, 0);
  int cur = 0;
  for (int sc = 0; sc < nchunk; ++sc) {
    int s0 = sc << 6;
    if (sc + 1 < nchunk) {
      STAGE(cur ^ 1, s0 + 64);                          // +8 in flight
      asm volatile("s_waitcnt vmcnt(8)" ::: "memory");  // cur's 8 done; prefetch flies on
    } else {
      asm volatile("s_waitcnt vmcnt(0)" ::: "memory");
    }
    __builtin_amdgcn_s_barrier();  // cur staged data visible to all waves
    if (s0 < smax_w) {
      char* kcur = (char*)Ks + cur * 16384;
      char* vcur = (char*)Vs + cur * 16384;
      // ---- swapped QK^T: st[t]; lane: q=l31, keys t*32+(r&3)+8*(r>>2)+4h
      f32x16 st[2];
      __builtin_amdgcn_s_setprio(1);
#pragma unroll
      for (int t = 0; t < 2; t++) {
        f32x16 a = {};
        int R = t * 32 + l31;
#pragma unroll
        for (int ks = 0; ks < 8; ks++) {
          int cl = 2 * ks + h;
          bf16x8 kf = *(const bf16x8*)(kcur + R * 256 + ((cl ^ (R & 15)) << 4));
          a = MFMA32(kf, qf[ks], a);
        }
        st[t] = a;
      }
      __builtin_amdgcn_s_setprio(0);
      // ---- causal mask (only diagonal chunks trigger)
      if (s0 + 63 > qw + SPAST_) {
        int q = qw + l31;
#pragma unroll
        for (int t = 0; t < 2; t++)
#pragma unroll
          for (int r = 0; r < 16; r++) {
            int key = s0 + t * 32 + (r & 3) + 8 * (r >> 2) + 4 * h;
            if (key > q + SPAST_) st[t][r] = -1e30f;
          }
      }
      // ---- online softmax: in-lane tree + 1 half-swap
      float mt = fmaxf(st[0][0], st[0][1]);
#pragma unroll
      for (int r = 2; r < 16; r++) mt = fmaxf(mt, st[0][r]);
#pragma unroll
      for (int r = 0; r < 16; r++) mt = fmaxf(mt, st[1][r]);
      mt = fmaxf(mt, __shfl_xor(mt, 32));
      if (__any(mt - mr > 8.0f)) {  // T13 defer-max
        float mn = fmaxf(mr, mt);
        float fac = exp2f(mr - mn);
        mr = mn;
        lr *= fac;
#pragma unroll
        for (int dt = 0; dt < 4; dt++) acc[dt] *= fac;
      }
      float s = 0.f;
#pragma unroll
      for (int t = 0; t < 2; t++)
#pragma unroll
        for (int r = 0; r < 16; r++) {
          float p = exp2f(st[t][r] - mr);
          st[t][r] = p;
          s += p;
        }
      s += __shfl_xor(s, 32);
      lr += s;
      // ---- P -> bf16 dwords + permlane32_swap (VDST.hi <-> VSRC.lo)
      uint32_t W[2][8];
#pragma unroll
      for (int t = 0; t < 2; t++)
#pragma unroll
        for (int j = 0; j < 8; j++)
          asm("v_cvt_pk_bf16_f32 %0, %1, %2"
              : "=v"(W[t][j])
              : "v"(st[t][2 * j]), "v"(st[t][2 * j + 1]));
#pragma unroll
      for (int t = 0; t < 2; t++)
#pragma unroll
        for (int s4 = 0; s4 < 8; s4 += 4) {
          asm volatile("v_permlane32_swap_b32 %0, %1" : "+v"(W[t][s4 + 0]), "+v"(W[t][s4 + 2]));
          asm volatile("v_permlane32_swap_b32 %0, %1" : "+v"(W[t][s4 + 1]), "+v"(W[t][s4 + 3]));
        }
      // ---- PV: O^T = V^T x P^T; A-frag from paired-row V LDS
      __builtin_amdgcn_s_setprio(1);
#pragma unroll
      for (int dt = 0; dt < 4; dt++) {
        int r = dt * 16 + (l31 >> 1);
        int clb = 8 * (l31 & 1) + h;
        f32x16 a = acc[dt];
#pragma unroll
        for (int ks = 0; ks < 4; ks++) {
          int cl = clb + 2 * ks;
          bf16x8 vf = *(const bf16x8*)(vcur + r * 256 + ((cl ^ (r & 15)) << 4));
          union { uint32_t u[4]; bf16x8 v; } pb;
          pb.u[0] = W[ks >> 1][(ks & 1) * 4 + 0];
          pb.u[1] = W[ks >> 1][(ks & 1) * 4 + 1];
          pb.u[2] = W[ks >> 1][(ks & 1) * 4 + 2];
          pb.u[3] = W[ks >> 1][(ks & 1) * 4 + 3];
          a = MFMA32(vf, pb.v, a);
        }
        acc[dt] = a;
      }
      __builtin_amdgcn_s_setprio(0);
    }
    __builtin_amdgcn_s_barrier();  // all waves done reading cur (next STAGE overwrites it)
    cur ^= 1;
  }
  // ---- epilogue: lane holds O[q=l31][d = dt*32+8u+4h+e] -> 8B stores
  {
    float inv = 1.0f / lr;
    int q = qw + l31;
    size_t base = ((size_t)(b * L_ + q) * H_ + hh) * D_;
#pragma unroll
    for (int dt = 0; dt < 4; dt++)
#pragma unroll
      for (int u = 0; u < 4; u++) {
        bf16x4 o;
#pragma unroll
        for (int e = 0; e < 4; e++) o[e] = (bf16)(acc[dt][4 * u + e] * inv);
        *(bf16x4*)(attnout + base + dt * 32 + 8 * u + 4 * h) = o;
      }
  }
}

extern "C" void kernel_launch(void* const* d_in, const int* in_sizes, int n_in,
                              void* d_out, int out_size, void* d_ws, size_t ws_size,
                              hipStream_t stream) {
  const float* x = (const float*)d_in[0];
  const float* wq = (const float*)d_in[1];
  const float* wk = (const float*)d_in[2];
  const float* wv = (const float*)d_in[3];
  const float* wo = (const float*)d_in[4];
  const float* bq = (const float*)d_in[5];
  const float* bk = (const float*)d_in[6];
  const float* bv = (const float*)d_in[7];
  const float* k_cache = (const float*)d_in[8];
  const float* v_cache = (const float*)d_in[9];
  const int* offp = (const int*)d_in[10];

  char* w = (char*)d_ws;
  size_t off = 0;
  auto alloc = [&](size_t bytes) -> char* {
    char* p = w + off;
    off += (bytes + 255) & ~(size_t)255;
    return p;
  };
  const size_t nBLE = (size_t)B_ * L_ * E_;
  const size_t nBLKV = (size_t)B_ * L_ * EKV_;
  const size_t nKV = (size_t)B_ * HKV_ * S_ * D_;
  bf16* xb = (bf16*)alloc(nBLE * 2);
  bf16* wqb = (bf16*)alloc((size_t)E_ * E_ * 2);
  bf16* wkb = (bf16*)alloc((size_t)EKV_ * E_ * 2);
  bf16* wvb = (bf16*)alloc((size_t)EKV_ * E_ * 2);
  bf16* wob = (bf16*)alloc((size_t)E_ * E_ * 2);
  bf16* q_lin = (bf16*)alloc(nBLE * 2);
  bf16* k_lin = (bf16*)alloc(nBLKV * 2);
  bf16* v_lin = (bf16*)alloc(nBLKV * 2);
  bf16* qbuf = (bf16*)alloc(nBLE * 2);
  bf16* k_all = (bf16*)alloc(nKV * 2);
  bf16* vtall = (bf16*)alloc(nKV * 2);
  bf16* attnout = (bf16*)alloc(nBLE * 2);
  float2* trig = (float2*)alloc((size_t)L_ * 64 * sizeof(float2));

  cvt_kernel<<<(int)(nBLE / 1024), 256, 0, stream>>>(x, xb, (int)nBLE);
  cvt_kernel<<<(int)((size_t)E_ * E_ / 1024), 256, 0, stream>>>(wq, wqb, E_ * E_);
  cvt_kernel<<<(int)((size_t)EKV_ * E_ / 1024), 256, 0, stream>>>(wk, wkb, EKV_ * E_);
  cvt_kernel<<<(int)((size_t)EKV_ * E_ / 1024), 256, 0, stream>>>(wv, wvb, EKV_ * E_);
  cvt_kernel<<<(int)((size_t)E_ * E_ / 1024), 256, 0, stream>>>(wo, wob, E_ * E_);
  trig_kernel<<<L_, 64, 0, stream>>>(offp, trig);

  const int M = B_ * L_;  // 4096
  gemm_nt<0><<<dim3(M / 128, E_ / 128), 256, 0, stream>>>(xb, wqb, bq, q_lin, M, E_, E_);
  gemm_nt<0><<<dim3(M / 128, EKV_ / 128), 256, 0, stream>>>(xb, wkb, bk, k_lin, M, EKV_, E_);
  gemm_nt<0><<<dim3(M / 128, EKV_ / 128), 256, 0, stream>>>(xb, wvb, bv, v_lin, M, EKV_, E_);
  rope_q_kernel<<<B_ * L_ / 2, 256, 0, stream>>>(q_lin, trig, qbuf);
  build_k_kernel<<<dim3(S_, B_ * HKV_), 128, 0, stream>>>(k_cache, k_lin, trig, k_all);
  build_vt_kernel<<<dim3(S_ / 64, D_ / 64, B_ * HKV_), 256, 0, stream>>>(v_cache, v_lin, vtall);
  attn_kernel<<<dim3(16, 32), 256, 0, stream>>>(qbuf, k_all, vtall, attnout);
  gemm_nt<1><<<dim3(M / 128, E_ / 128), 256, 0, stream>>>(attnout, wob, nullptr, d_out, M, E_, E_);
}

// Round 13
// 321.516 us; speedup vs baseline: 1.2991x; 1.0727x over previous
//
#include <hip/hip_runtime.h>
#include <hip/hip_bf16.h>
#include <stdint.h>

typedef __bf16 bf16;
typedef __bf16 bf16x8 __attribute__((ext_vector_type(8)));
typedef __bf16 bf16x4 __attribute__((ext_vector_type(4)));
typedef float f32x4 __attribute__((ext_vector_type(4)));
typedef float f32x16 __attribute__((ext_vector_type(16)));

#define B_ 2
#define L_ 2048
#define E_ 2048
#define H_ 16
#define HKV_ 2
#define G_ 8
#define D_ 128
#define SPAST_ 2048
#define S_ 4096
#define EKV_ 256

#define MFMA16(a, b, c) __builtin_amdgcn_mfma_f32_16x16x32_bf16(a, b, c, 0, 0, 0)
#define MFMA32(a, b, c) __builtin_amdgcn_mfma_f32_32x32x16_bf16(a, b, c, 0, 0, 0)

__device__ __forceinline__ void gload16(const bf16* g, bf16* l) {
  __builtin_amdgcn_global_load_lds(
      (__attribute__((address_space(1))) void*)g,
      (__attribute__((address_space(3))) void*)l, 16, 0, 0);
}

// ---------------- f32 -> bf16 conversion ----------------
__global__ void cvt_kernel(const float* __restrict__ src, bf16* __restrict__ dst, int n) {
  int i = (blockIdx.x * 256 + threadIdx.x) * 4;
  if (i >= n) return;
  float4 v = *(const float4*)(src + i);
  bf16x4 o;
  o[0] = (bf16)v.x; o[1] = (bf16)v.y; o[2] = (bf16)v.z; o[3] = (bf16)v.w;
  *(bf16x4*)(dst + i) = o;
}

// ---------------- trig table ----------------
__global__ void trig_kernel(const int* __restrict__ offp, float2* __restrict__ trig) {
  int l = blockIdx.x, j = threadIdx.x;  // 64 threads
  float inv = exp2f(-(float)j * (13.287712379549449f / 64.0f));  // log2(10000)
  float ang = (float)(*offp + l) * inv;
  trig[l * 64 + j] = make_float2(cosf(ang), sinf(ang));
}

// ---------------- NT GEMM (R9-proven): 2-phase dbuf, __syncthreads ----------------
template <int OUTF32>
__global__ __launch_bounds__(256) void gemm_nt(const bf16* __restrict__ A,
                                               const bf16* __restrict__ Bw,
                                               const float* __restrict__ bias,
                                               void* __restrict__ Cout,
                                               int M, int N, int K) {
  __shared__ bf16 As[2 * 128 * 64];
  __shared__ bf16 Bs[2 * 128 * 64];
  const int tid = threadIdx.x;
  const int wid = tid >> 6, lane = tid & 63;
  const int ln15 = lane & 15, lq = lane >> 4;
  const int row0 = blockIdx.x * 128, col0 = blockIdx.y * 128;
  const int wr = wid >> 1, wc = wid & 1;
  f32x4 acc[4][4] = {};
  char* AsB = (char*)As;
  char* BsB = (char*)Bs;

  auto STAGE = [&](int buf, int k0) {
    char* ad = AsB + buf * 16384;
    char* bd = BsB + buf * 16384;
#pragma unroll
    for (int j = 0; j < 4; j++) {
      int cid = j * 256 + tid;
      int r = cid >> 3, c = cid & 7;
      int csw = (c ^ (r & 7)) << 3;
      gload16(A + (size_t)(row0 + r) * K + k0 + csw, (bf16*)(ad + (j * 256 + wid * 64) * 16));
      gload16(Bw + (size_t)(col0 + r) * K + k0 + csw, (bf16*)(bd + (j * 256 + wid * 64) * 16));
    }
  };

  STAGE(0, 0);
  __syncthreads();
  int cur = 0;
  for (int k0 = 0; k0 < K; k0 += 64) {
    if (k0 + 64 < K) STAGE(cur ^ 1, k0 + 64);
    char* ac = AsB + cur * 16384;
    char* bc = BsB + cur * 16384;
    bf16x8 af[4][2], bfm[4][2];
#pragma unroll
    for (int m = 0; m < 4; m++) {
#pragma unroll
      for (int kk = 0; kk < 2; kk++) {
        int Ra = wr * 64 + m * 16 + ln15;
        int Rb = wc * 64 + m * 16 + ln15;
        int c = (kk << 2) + lq;
        af[m][kk] = *(const bf16x8*)(ac + Ra * 128 + ((c ^ (Ra & 7)) << 4));
        bfm[m][kk] = *(const bf16x8*)(bc + Rb * 128 + ((c ^ (Rb & 7)) << 4));
      }
    }
    __builtin_amdgcn_s_setprio(1);
#pragma unroll
    for (int m = 0; m < 4; m++)
#pragma unroll
      for (int n = 0; n < 4; n++)
#pragma unroll
        for (int kk = 0; kk < 2; kk++)
          acc[m][n] = MFMA16(af[m][kk], bfm[n][kk], acc[m][n]);
    __builtin_amdgcn_s_setprio(0);
    __syncthreads();
    cur ^= 1;
  }
#pragma unroll
  for (int m = 0; m < 4; m++) {
    int gr0 = row0 + wr * 64 + m * 16 + 4 * lq;
#pragma unroll
    for (int n = 0; n < 4; n++) {
      int gc = col0 + wc * 64 + n * 16 + ln15;
      float bv = bias ? bias[gc] : 0.0f;
#pragma unroll
      for (int reg = 0; reg < 4; reg++) {
        float v = acc[m][n][reg] + bv;
        size_t idx = (size_t)(gr0 + reg) * N + gc;
        if (OUTF32)
          ((float*)Cout)[idx] = v;
        else
          ((bf16*)Cout)[idx] = (bf16)v;
      }
    }
  }
}

// ---------------- RoPE on Q (vectorized bf16x8), fold softmax scale*log2e ----------------
__global__ void rope_q_kernel(const bf16* __restrict__ q_lin, const float2* __restrict__ trig,
                              bf16* __restrict__ qbuf) {
  int bl = blockIdx.x * 2 + (threadIdx.x >> 7);  // grid = B*L/2
  int b = bl >> 11, l = bl & 2047;
  int u = threadIdx.x & 127;
  int h = u >> 3, j0 = (u & 7) * 8;
  const float QS = 0.08838834764831845f * 1.4426950408889634f;  // 1/sqrt(128) * log2(e)
  const bf16* src = q_lin + (size_t)bl * E_ + h * D_ + j0;
  bf16x8 x1 = *(const bf16x8*)(src);
  bf16x8 x2 = *(const bf16x8*)(src + 64);
  bf16x8 o1, o2;
#pragma unroll
  for (int e = 0; e < 8; e++) {
    float2 cs = trig[l * 64 + j0 + e];
    float a = (float)x1[e], c = (float)x2[e];
    o1[e] = (bf16)((a * cs.x - c * cs.y) * QS);
    o2[e] = (bf16)((c * cs.x + a * cs.y) * QS);
  }
  size_t o = ((size_t)(b * H_ + h) * L_ + l) * D_ + j0;
  *(bf16x8*)(qbuf + o) = o1;
  *(bf16x8*)(qbuf + o + 64) = o2;
}

// ---------------- build k_all (B,HKV,S,D) ----------------
__global__ void build_k_kernel(const float* __restrict__ k_cache, const bf16* __restrict__ k_lin,
                               const float2* __restrict__ trig, bf16* __restrict__ k_all) {
  int d = threadIdx.x;  // 128
  int s = blockIdx.x;
  int bz = blockIdx.y;  // b*HKV + hkv
  size_t oidx = ((size_t)bz * S_ + s) * D_ + d;
  if (s < SPAST_) {
    k_all[oidx] = (bf16)k_cache[((size_t)bz * SPAST_ + s) * D_ + d];
  } else {
    int l = s - SPAST_;
    int b = bz >> 1, kh = bz & 1;
    int j = d & 63;
    float2 cs = trig[l * 64 + j];
    size_t base = (size_t)(b * L_ + l) * EKV_ + kh * D_;
    float x1 = (float)k_lin[base + j];
    float x2 = (float)k_lin[base + 64 + j];
    float v = (d < 64) ? (x1 * cs.x - x2 * cs.y) : (x2 * cs.x + x1 * cs.y);
    k_all[oidx] = (bf16)v;
  }
}

// ---------------- build transposed V: vtall (B,HKV,D,S) (vectorized) ----------------
__global__ void build_vt_kernel(const float* __restrict__ v_cache, const bf16* __restrict__ v_lin,
                                bf16* __restrict__ vtall) {
  __shared__ float tile[64][68];
  int s0 = blockIdx.x * 64;
  int d0 = blockIdx.y * 64;
  int bz = blockIdx.z;
  int b = bz >> 1, kh = bz & 1;
#pragma unroll
  for (int it = 0; it < 4; it++) {
    int idx = it * 256 + threadIdx.x;  // 0..1023
    int ss = idx >> 4, dd0 = (idx & 15) * 4;
    int s = s0 + ss;
    float4 v;
    if (s < SPAST_) {
      v = *(const float4*)(v_cache + ((size_t)bz * SPAST_ + s) * D_ + d0 + dd0);
    } else {
      bf16x4 t = *(const bf16x4*)(v_lin + (size_t)(b * L_ + (s - SPAST_)) * EKV_ + kh * D_ + d0 + dd0);
      v = make_float4((float)t[0], (float)t[1], (float)t[2], (float)t[3]);
    }
    tile[ss][dd0] = v.x; tile[ss][dd0 + 1] = v.y;
    tile[ss][dd0 + 2] = v.z; tile[ss][dd0 + 3] = v.w;
  }
  __syncthreads();
#pragma unroll
  for (int it = 0; it < 4; it++) {
    int idx = it * 256 + threadIdx.x;
    int dd = idx >> 4, ss0 = (idx & 15) * 4;
    bf16x4 o;
#pragma unroll
    for (int e = 0; e < 4; e++) o[e] = (bf16)tile[ss0 + e][dd];
    *(bf16x4*)(vtall + ((size_t)bz * D_ + d0 + dd) * S_ + s0 + ss0) = o;
  }
}

// ---------------- flash attention: 1-stage software pipeline (T15 analog) ----------------
// grid (16, 32); 4 waves x 32 q-rows; 64-key chunks, K/V each double-buffered.
// Per iter: QK^T(i+1) issued FIRST (MFMA pipe), then SK(i+2)/SV(i+1) staging flies under
// FIN(i) = mask+softmax+cvt_pk/permlane+PV (VALU/LDS pipes). Unrolled x2 (nchunk even)
// with named stA/stB score sets (no runtime indexing). One vmcnt(0)+barrier per chunk.
// Buffer disjointness per iter i: writes {K[i&1], V[(i+1)&1]} vs reads {K[(i+1)&1], V[i&1]}.
__global__ __launch_bounds__(256, 2) void attn_kernel(const bf16* __restrict__ qbuf,
                                                      const bf16* __restrict__ k_all,
                                                      const bf16* __restrict__ vtall,
                                                      bf16* __restrict__ attnout) {
  __shared__ bf16 Ks[2 * 64 * 128];   // [key][d], 256B rows, swizzled 16B slots
  __shared__ bf16 Vs[2 * 64 * 128];   // paired rows: row r = {d=2r | d=2r+1}, 256B
  const int tid = threadIdx.x;
  const int wid = tid >> 6, lane = tid & 63;
  const int l31 = lane & 31, h = lane >> 5;
  const int xq = ((blockIdx.y >> 4) & 1) ? (15 - (int)blockIdx.x) : (int)blockIdx.x;
  const int q0 = xq * 128;
  const int bh = blockIdx.y;
  const int b = bh / H_, hh = bh % H_;
  const int hkv = hh / G_;
  const bf16* kb = k_all + (size_t)(b * HKV_ + hkv) * S_ * D_;
  const bf16* vb = vtall + (size_t)(b * HKV_ + hkv) * D_ * S_;
  const int qw = q0 + wid * 32;
  bf16x8 qf[8];
  {
    const bf16* qp = qbuf + ((size_t)(b * H_ + hh) * L_ + qw + l31) * D_ + h * 8;
#pragma unroll
    for (int ks = 0; ks < 8; ks++) qf[ks] = *(const bf16x8*)(qp + ks * 16);
  }
  f32x16 acc[4] = {};
  float mr = -3e38f, lr = 0.f;

  auto SK = [&](int buf, int s0) {  // 4 loads/thread: K chunk 64x128
    char* kd = (char*)Ks + buf * 16384;
#pragma unroll
    for (int j = 0; j < 4; j++) {
      int cid = j * 256 + tid;
      int r = cid >> 4;
      int cl = (cid & 15) ^ (r & 15);
      gload16(kb + (size_t)(s0 + r) * D_ + cl * 8, (bf16*)(kd + (j * 256 + wid * 64) * 16));
    }
  };
  auto SV = [&](int buf, int s0) {  // 4 loads/thread: V^T chunk, paired d-rows
    char* vd = (char*)Vs + buf * 16384;
#pragma unroll
    for (int j = 0; j < 4; j++) {
      int cid = j * 256 + tid;
      int r = cid >> 4;
      int cl = (cid & 15) ^ (r & 15);
      gload16(vb + (size_t)(2 * r + (cl >> 3)) * S_ + s0 + (cl & 7) * 8,
              (bf16*)(vd + (j * 256 + wid * 64) * 16));
    }
  };

  auto QKT = [&](int buf, f32x16& o0, f32x16& o1) {
    char* kcur = (char*)Ks + buf * 16384;
    __builtin_amdgcn_s_setprio(1);
    {
      f32x16 a = {};
      int R = l31;
#pragma unroll
      for (int ks = 0; ks < 8; ks++) {
        int cl = 2 * ks + h;
        bf16x8 kf = *(const bf16x8*)(kcur + R * 256 + ((cl ^ (R & 15)) << 4));
        a = MFMA32(kf, qf[ks], a);
      }
      o0 = a;
    }
    {
      f32x16 a = {};
      int R = 32 + l31;
#pragma unroll
      for (int ks = 0; ks < 8; ks++) {
        int cl = 2 * ks + h;
        bf16x8 kf = *(const bf16x8*)(kcur + R * 256 + ((cl ^ (R & 15)) << 4));
        a = MFMA32(kf, qf[ks], a);
      }
      o1 = a;
    }
    __builtin_amdgcn_s_setprio(0);
  };

  auto FIN = [&](f32x16& st0, f32x16& st1, int s0, int vbuf) {
    char* vcur = (char*)Vs + vbuf * 16384;
    // ---- causal mask (diagonal chunks only)
    if (s0 + 63 > qw + SPAST_) {
      int q = qw + l31;
#pragma unroll
      for (int r = 0; r < 16; r++) {
        int key0 = s0 + (r & 3) + 8 * (r >> 2) + 4 * h;
        if (key0 > q + SPAST_) st0[r] = -1e30f;
        if (key0 + 32 > q + SPAST_) st1[r] = -1e30f;
      }
    }
    // ---- tree max (depth ~5) + 1 half-swap
    float t0 = fmaxf(fmaxf(st0[0], st0[1]), fmaxf(st0[2], st0[3]));
    float t1 = fmaxf(fmaxf(st0[4], st0[5]), fmaxf(st0[6], st0[7]));
    float t2 = fmaxf(fmaxf(st0[8], st0[9]), fmaxf(st0[10], st0[11]));
    float t3 = fmaxf(fmaxf(st0[12], st0[13]), fmaxf(st0[14], st0[15]));
    float u0 = fmaxf(fmaxf(st1[0], st1[1]), fmaxf(st1[2], st1[3]));
    float u1 = fmaxf(fmaxf(st1[4], st1[5]), fmaxf(st1[6], st1[7]));
    float u2 = fmaxf(fmaxf(st1[8], st1[9]), fmaxf(st1[10], st1[11]));
    float u3 = fmaxf(fmaxf(st1[12], st1[13]), fmaxf(st1[14], st1[15]));
    float mt = fmaxf(fmaxf(fmaxf(t0, t1), fmaxf(t2, t3)),
                     fmaxf(fmaxf(u0, u1), fmaxf(u2, u3)));
    mt = fmaxf(mt, __shfl_xor(mt, 32));
    if (__any(mt - mr > 8.0f)) {  // T13 defer-max
      float mn = fmaxf(mr, mt);
      float fac = exp2f(mr - mn);
      mr = mn;
      lr *= fac;
#pragma unroll
      for (int dt = 0; dt < 4; dt++) acc[dt] *= fac;
    }
    // ---- exp + tree sum
    float sacc[4] = {0.f, 0.f, 0.f, 0.f};
#pragma unroll
    for (int r = 0; r < 16; r++) {
      float p = exp2f(st0[r] - mr);
      st0[r] = p;
      sacc[r & 3] += p;
    }
#pragma unroll
    for (int r = 0; r < 16; r++) {
      float p = exp2f(st1[r] - mr);
      st1[r] = p;
      sacc[r & 3] += p;
    }
    float s = (sacc[0] + sacc[1]) + (sacc[2] + sacc[3]);
    s += __shfl_xor(s, 32);
    lr += s;
    // ---- P -> bf16 dwords + permlane32_swap (VDST.hi <-> VSRC.lo)
    uint32_t W[2][8];
#pragma unroll
    for (int j = 0; j < 8; j++)
      asm("v_cvt_pk_bf16_f32 %0, %1, %2" : "=v"(W[0][j]) : "v"(st0[2 * j]), "v"(st0[2 * j + 1]));
#pragma unroll
    for (int j = 0; j < 8; j++)
      asm("v_cvt_pk_bf16_f32 %0, %1, %2" : "=v"(W[1][j]) : "v"(st1[2 * j]), "v"(st1[2 * j + 1]));
#pragma unroll
    for (int t = 0; t < 2; t++)
#pragma unroll
      for (int s4 = 0; s4 < 8; s4 += 4) {
        asm volatile("v_permlane32_swap_b32 %0, %1" : "+v"(W[t][s4 + 0]), "+v"(W[t][s4 + 2]));
        asm volatile("v_permlane32_swap_b32 %0, %1" : "+v"(W[t][s4 + 1]), "+v"(W[t][s4 + 3]));
      }
    // ---- PV: O^T = V^T x P^T
    __builtin_amdgcn_s_setprio(1);
#pragma unroll
    for (int dt = 0; dt < 4; dt++) {
      int r = dt * 16 + (l31 >> 1);
      int clb = 8 * (l31 & 1) + h;
      f32x16 a = acc[dt];
#pragma unroll
      for (int ks = 0; ks < 4; ks++) {
        int cl = clb + 2 * ks;
        bf16x8 vf = *(const bf16x8*)(vcur + r * 256 + ((cl ^ (r & 15)) << 4));
        union { uint32_t u[4]; bf16x8 v; } pb;
        pb.u[0] = W[ks >> 1][(ks & 1) * 4 + 0];
        pb.u[1] = W[ks >> 1][(ks & 1) * 4 + 1];
        pb.u[2] = W[ks >> 1][(ks & 1) * 4 + 2];
        pb.u[3] = W[ks >> 1][(ks & 1) * 4 + 3];
        a = MFMA32(vf, pb.v, a);
      }
      acc[dt] = a;
    }
    __builtin_amdgcn_s_setprio(0);
  };

  const int nchunk = (q0 + 128 + SPAST_) >> 6;  // 34 + 2*xq, always even
  const int smax_w = qw + 32 + SPAST_;

  // prologue: K(0),V(0),K(1); compute st(0)
  SK(0, 0);
  SV(0, 0);
  SK(1, 64);
  asm volatile("s_waitcnt vmcnt(4)" ::: "memory");  // K(0),V(0) complete; K(1) in flight
  __builtin_amdgcn_s_barrier();
  f32x16 sA0, sA1, sB0, sB1;
  QKT(0, sA0, sA1);

  for (int i = 0; i < nchunk; i += 2) {
    // ---- body A: finish chunk i (stA), produce chunk i+1 (stB)
    asm volatile("s_waitcnt vmcnt(0)" ::: "memory");  // K(i+1), V(i) staged
    __builtin_amdgcn_s_barrier();
    if (i + 1 < nchunk && (i + 1) * 64 < smax_w) QKT((i + 1) & 1, sB0, sB1);
    if (i + 2 < nchunk) SK(i & 1, (i + 2) * 64);       // K(i+2) -> K[i&1]
    if (i + 1 < nchunk) SV((i + 1) & 1, (i + 1) * 64); // V(i+1) -> V[(i+1)&1]
    if (i * 64 < smax_w) FIN(sA0, sA1, i * 64, i & 1);
    // ---- body B: finish chunk i+1 (stB), produce chunk i+2 (stA)
    asm volatile("s_waitcnt vmcnt(0)" ::: "memory");  // K(i+2), V(i+1) staged
    __builtin_amdgcn_s_barrier();
    if (i + 2 < nchunk && (i + 2) * 64 < smax_w) QKT(i & 1, sA0, sA1);
    if (i + 3 < nchunk) SK((i + 1) & 1, (i + 3) * 64); // K(i+3) -> K[(i+1)&1]
    if (i + 2 < nchunk) SV(i & 1, (i + 2) * 64);       // V(i+2) -> V[i&1]
    if ((i + 1) * 64 < smax_w) FIN(sB0, sB1, (i + 1) * 64, (i + 1) & 1);
  }
  // ---- epilogue: lane holds O[q=l31][d = dt*32+8u+4h+e] -> 8B stores
  {
    float inv = 1.0f / lr;
    int q = qw + l31;
    size_t base = ((size_t)(b * L_ + q) * H_ + hh) * D_;
#pragma unroll
    for (int dt = 0; dt < 4; dt++)
#pragma unroll
      for (int u = 0; u < 4; u++) {
        bf16x4 o;
#pragma unroll
        for (int e = 0; e < 4; e++) o[e] = (bf16)(acc[dt][4 * u + e] * inv);
        *(bf16x4*)(attnout + base + dt * 32 + 8 * u + 4 * h) = o;
      }
  }
}

extern "C" void kernel_launch(void* const* d_in, const int* in_sizes, int n_in,
                              void* d_out, int out_size, void* d_ws, size_t ws_size,
                              hipStream_t stream) {
  const float* x = (const float*)d_in[0];
  const float* wq = (const float*)d_in[1];
  const float* wk = (const float*)d_in[2];
  const float* wv = (const float*)d_in[3];
  const float* wo = (const float*)d_in[4];
  const float* bq = (const float*)d_in[5];
  const float* bk = (const float*)d_in[6];
  const float* bv = (const float*)d_in[7];
  const float* k_cache = (const float*)d_in[8];
  const float* v_cache = (const float*)d_in[9];
  const int* offp = (const int*)d_in[10];

  char* w = (char*)d_ws;
  size_t off = 0;
  auto alloc = [&](size_t bytes) -> char* {
    char* p = w + off;
    off += (bytes + 255) & ~(size_t)255;
    return p;
  };
  const size_t nBLE = (size_t)B_ * L_ * E_;
  const size_t nBLKV = (size_t)B_ * L_ * EKV_;
  const size_t nKV = (size_t)B_ * HKV_ * S_ * D_;
  bf16* xb = (bf16*)alloc(nBLE * 2);
  bf16* wqb = (bf16*)alloc((size_t)E_ * E_ * 2);
  bf16* wkb = (bf16*)alloc((size_t)EKV_ * E_ * 2);
  bf16* wvb = (bf16*)alloc((size_t)EKV_ * E_ * 2);
  bf16* wob = (bf16*)alloc((size_t)E_ * E_ * 2);
  bf16* q_lin = (bf16*)alloc(nBLE * 2);
  bf16* k_lin = (bf16*)alloc(nBLKV * 2);
  bf16* v_lin = (bf16*)alloc(nBLKV * 2);
  bf16* qbuf = (bf16*)alloc(nBLE * 2);
  bf16* k_all = (bf16*)alloc(nKV * 2);
  bf16* vtall = (bf16*)alloc(nKV * 2);
  bf16* attnout = (bf16*)alloc(nBLE * 2);
  float2* trig = (float2*)alloc((size_t)L_ * 64 * sizeof(float2));

  cvt_kernel<<<(int)(nBLE / 1024), 256, 0, stream>>>(x, xb, (int)nBLE);
  cvt_kernel<<<(int)((size_t)E_ * E_ / 1024), 256, 0, stream>>>(wq, wqb, E_ * E_);
  cvt_kernel<<<(int)((size_t)EKV_ * E_ / 1024), 256, 0, stream>>>(wk, wkb, EKV_ * E_);
  cvt_kernel<<<(int)((size_t)EKV_ * E_ / 1024), 256, 0, stream>>>(wv, wvb, EKV_ * E_);
  cvt_kernel<<<(int)((size_t)E_ * E_ / 1024), 256, 0, stream>>>(wo, wob, E_ * E_);
  trig_kernel<<<L_, 64, 0, stream>>>(offp, trig);

  const int M = B_ * L_;  // 4096
  gemm_nt<0><<<dim3(M / 128, E_ / 128), 256, 0, stream>>>(xb, wqb, bq, q_lin, M, E_, E_);
  gemm_nt<0><<<dim3(M / 128, EKV_ / 128), 256, 0, stream>>>(xb, wkb, bk, k_lin, M, EKV_, E_);
  gemm_nt<0><<<dim3(M / 128, EKV_ / 128), 256, 0, stream>>>(xb, wvb, bv, v_lin, M, EKV_, E_);
  rope_q_kernel<<<B_ * L_ / 2, 256, 0, stream>>>(q_lin, trig, qbuf);
  build_k_kernel<<<dim3(S_, B_ * HKV_), 128, 0, stream>>>(k_cache, k_lin, trig, k_all);
  build_vt_kernel<<<dim3(S_ / 64, D_ / 64, B_ * HKV_), 256, 0, stream>>>(v_cache, v_lin, vtall);
  attn_kernel<<<dim3(16, 32), 256, 0, stream>>>(qbuf, k_all, vtall, attnout);
  gemm_nt<1><<<dim3(M / 128, E_ / 128), 256, 0, stream>>>(attnout, wob, nullptr, d_out, M, E_, E_);
}

// Round 14
// 291.052 us; speedup vs baseline: 1.4351x; 1.1047x over previous
//
#include <hip/hip_runtime.h>
#include <hip/hip_bf16.h>
#include <stdint.h>

typedef __bf16 bf16;
typedef __bf16 bf16x8 __attribute__((ext_vector_type(8)));
typedef __bf16 bf16x4 __attribute__((ext_vector_type(4)));
typedef float f32x4 __attribute__((ext_vector_type(4)));
typedef float f32x16 __attribute__((ext_vector_type(16)));

#define B_ 2
#define L_ 2048
#define E_ 2048
#define H_ 16
#define HKV_ 2
#define G_ 8
#define D_ 128
#define SPAST_ 2048
#define S_ 4096
#define EKV_ 256
#define QKVN 2560   // fused projection width: E + 2*EKV
#define KOFF 2048   // k columns start
#define VOFF 2304   // v columns start

#define MFMA16(a, b, c) __builtin_amdgcn_mfma_f32_16x16x32_bf16(a, b, c, 0, 0, 0)
#define MFMA32(a, b, c) __builtin_amdgcn_mfma_f32_32x32x16_bf16(a, b, c, 0, 0, 0)

__device__ __forceinline__ void gload16(const bf16* g, bf16* l) {
  __builtin_amdgcn_global_load_lds(
      (__attribute__((address_space(1))) void*)g,
      (__attribute__((address_space(3))) void*)l, 16, 0, 0);
}

// ---------------- fused f32 -> bf16 conversion: 5 buffers, one launch ----------------
// block ranges: x[0,8192) wq[8192,12288) wk[12288,12800) wv[12800,13312) wo[13312,17408)
__global__ void cvt5_kernel(const float* __restrict__ sx, const float* __restrict__ swq,
                            const float* __restrict__ swk, const float* __restrict__ swv,
                            const float* __restrict__ swo, bf16* __restrict__ dx,
                            bf16* __restrict__ dwqkv, bf16* __restrict__ dwo) {
  int blk = blockIdx.x;
  const float* s;
  bf16* d;
  int base;
  if (blk < 8192) { s = sx; d = dx; base = blk; }
  else if (blk < 12288) { s = swq; d = dwqkv; base = blk - 8192; }
  else if (blk < 12800) { s = swk; d = dwqkv + (size_t)E_ * E_; base = blk - 12288; }
  else if (blk < 13312) { s = swv; d = dwqkv + (size_t)(E_ + EKV_) * E_; base = blk - 12800; }
  else { s = swo; d = dwo; base = blk - 13312; }
  size_t i = ((size_t)base * 256 + threadIdx.x) * 4;
  float4 v = *(const float4*)(s + i);
  bf16x4 o;
  o[0] = (bf16)v.x; o[1] = (bf16)v.y; o[2] = (bf16)v.z; o[3] = (bf16)v.w;
  *(bf16x4*)(d + i) = o;
}

// ---------------- trig table ----------------
__global__ void trig_kernel(const int* __restrict__ offp, float2* __restrict__ trig) {
  int l = blockIdx.x, j = threadIdx.x;  // 64 threads
  float inv = exp2f(-(float)j * (13.287712379549449f / 64.0f));  // log2(10000)
  float ang = (float)(*offp + l) * inv;
  trig[l * 64 + j] = make_float2(cosf(ang), sinf(ang));
}

// ---------------- concat biases: cb[0..2048)=bq, [2048..2304)=bk, [2304..2560)=bv ----------------
__global__ void biascat_kernel(const float* __restrict__ bq, const float* __restrict__ bk,
                               const float* __restrict__ bv, float* __restrict__ cb) {
  int i = blockIdx.x * 256 + threadIdx.x;  // grid 10 x 256 = 2560
  float v;
  if (i < E_) v = bq[i];
  else if (i < E_ + EKV_) v = bk[i - E_];
  else v = bv[i - E_ - EKV_];
  cb[i] = v;
}

// ---------------- NT GEMM (R9-proven): 2-phase dbuf, __syncthreads ----------------
template <int OUTF32>
__global__ __launch_bounds__(256) void gemm_nt(const bf16* __restrict__ A,
                                               const bf16* __restrict__ Bw,
                                               const float* __restrict__ bias,
                                               void* __restrict__ Cout,
                                               int M, int N, int K) {
  __shared__ bf16 As[2 * 128 * 64];
  __shared__ bf16 Bs[2 * 128 * 64];
  const int tid = threadIdx.x;
  const int wid = tid >> 6, lane = tid & 63;
  const int ln15 = lane & 15, lq = lane >> 4;
  const int row0 = blockIdx.x * 128, col0 = blockIdx.y * 128;
  const int wr = wid >> 1, wc = wid & 1;
  f32x4 acc[4][4] = {};
  char* AsB = (char*)As;
  char* BsB = (char*)Bs;

  auto STAGE = [&](int buf, int k0) {
    char* ad = AsB + buf * 16384;
    char* bd = BsB + buf * 16384;
#pragma unroll
    for (int j = 0; j < 4; j++) {
      int cid = j * 256 + tid;
      int r = cid >> 3, c = cid & 7;
      int csw = (c ^ (r & 7)) << 3;
      gload16(A + (size_t)(row0 + r) * K + k0 + csw, (bf16*)(ad + (j * 256 + wid * 64) * 16));
      gload16(Bw + (size_t)(col0 + r) * K + k0 + csw, (bf16*)(bd + (j * 256 + wid * 64) * 16));
    }
  };

  STAGE(0, 0);
  __syncthreads();
  int cur = 0;
  for (int k0 = 0; k0 < K; k0 += 64) {
    if (k0 + 64 < K) STAGE(cur ^ 1, k0 + 64);
    char* ac = AsB + cur * 16384;
    char* bc = BsB + cur * 16384;
    bf16x8 af[4][2], bfm[4][2];
#pragma unroll
    for (int m = 0; m < 4; m++) {
#pragma unroll
      for (int kk = 0; kk < 2; kk++) {
        int Ra = wr * 64 + m * 16 + ln15;
        int Rb = wc * 64 + m * 16 + ln15;
        int c = (kk << 2) + lq;
        af[m][kk] = *(const bf16x8*)(ac + Ra * 128 + ((c ^ (Ra & 7)) << 4));
        bfm[m][kk] = *(const bf16x8*)(bc + Rb * 128 + ((c ^ (Rb & 7)) << 4));
      }
    }
    __builtin_amdgcn_s_setprio(1);
#pragma unroll
    for (int m = 0; m < 4; m++)
#pragma unroll
      for (int n = 0; n < 4; n++)
#pragma unroll
        for (int kk = 0; kk < 2; kk++)
          acc[m][n] = MFMA16(af[m][kk], bfm[n][kk], acc[m][n]);
    __builtin_amdgcn_s_setprio(0);
    __syncthreads();
    cur ^= 1;
  }
#pragma unroll
  for (int m = 0; m < 4; m++) {
    int gr0 = row0 + wr * 64 + m * 16 + 4 * lq;
#pragma unroll
    for (int n = 0; n < 4; n++) {
      int gc = col0 + wc * 64 + n * 16 + ln15;
      float bv = bias ? bias[gc] : 0.0f;
#pragma unroll
      for (int reg = 0; reg < 4; reg++) {
        float v = acc[m][n][reg] + bv;
        size_t idx = (size_t)(gr0 + reg) * N + gc;
        if (OUTF32)
          ((float*)Cout)[idx] = v;
        else
          ((bf16*)Cout)[idx] = (bf16)v;
      }
    }
  }
}

// ---------------- RoPE on Q (vectorized bf16x8), reads fused qkv_lin ----------------
__global__ void rope_q_kernel(const bf16* __restrict__ qkv_lin, const float2* __restrict__ trig,
                              bf16* __restrict__ qbuf) {
  int bl = blockIdx.x * 2 + (threadIdx.x >> 7);  // grid = B*L/2
  int b = bl >> 11, l = bl & 2047;
  int u = threadIdx.x & 127;
  int h = u >> 3, j0 = (u & 7) * 8;
  const float QS = 0.08838834764831845f * 1.4426950408889634f;  // 1/sqrt(128) * log2(e)
  const bf16* src = qkv_lin + (size_t)bl * QKVN + h * D_ + j0;
  bf16x8 x1 = *(const bf16x8*)(src);
  bf16x8 x2 = *(const bf16x8*)(src + 64);
  bf16x8 o1, o2;
#pragma unroll
  for (int e = 0; e < 8; e++) {
    float2 cs = trig[l * 64 + j0 + e];
    float a = (float)x1[e], c = (float)x2[e];
    o1[e] = (bf16)((a * cs.x - c * cs.y) * QS);
    o2[e] = (bf16)((c * cs.x + a * cs.y) * QS);
  }
  size_t o = ((size_t)(b * H_ + h) * L_ + l) * D_ + j0;
  *(bf16x8*)(qbuf + o) = o1;
  *(bf16x8*)(qbuf + o + 64) = o2;
}

// ---------------- build k_all (B,HKV,S,D), reads fused qkv_lin ----------------
__global__ void build_k_kernel(const float* __restrict__ k_cache, const bf16* __restrict__ qkv_lin,
                               const float2* __restrict__ trig, bf16* __restrict__ k_all) {
  int d = threadIdx.x;  // 128
  int s = blockIdx.x;
  int bz = blockIdx.y;  // b*HKV + hkv
  size_t oidx = ((size_t)bz * S_ + s) * D_ + d;
  if (s < SPAST_) {
    k_all[oidx] = (bf16)k_cache[((size_t)bz * SPAST_ + s) * D_ + d];
  } else {
    int l = s - SPAST_;
    int b = bz >> 1, kh = bz & 1;
    int j = d & 63;
    float2 cs = trig[l * 64 + j];
    size_t base = (size_t)(b * L_ + l) * QKVN + KOFF + kh * D_;
    float x1 = (float)qkv_lin[base + j];
    float x2 = (float)qkv_lin[base + 64 + j];
    float v = (d < 64) ? (x1 * cs.x - x2 * cs.y) : (x2 * cs.x + x1 * cs.y);
    k_all[oidx] = (bf16)v;
  }
}

// ---------------- build transposed V: vtall (B,HKV,D,S), reads fused qkv_lin ----------------
__global__ void build_vt_kernel(const float* __restrict__ v_cache, const bf16* __restrict__ qkv_lin,
                                bf16* __restrict__ vtall) {
  __shared__ float tile[64][68];
  int s0 = blockIdx.x * 64;
  int d0 = blockIdx.y * 64;
  int bz = blockIdx.z;
  int b = bz >> 1, kh = bz & 1;
#pragma unroll
  for (int it = 0; it < 4; it++) {
    int idx = it * 256 + threadIdx.x;  // 0..1023
    int ss = idx >> 4, dd0 = (idx & 15) * 4;
    int s = s0 + ss;
    float4 v;
    if (s < SPAST_) {
      v = *(const float4*)(v_cache + ((size_t)bz * SPAST_ + s) * D_ + d0 + dd0);
    } else {
      bf16x4 t = *(const bf16x4*)(qkv_lin + (size_t)(b * L_ + (s - SPAST_)) * QKVN + VOFF +
                                  kh * D_ + d0 + dd0);
      v = make_float4((float)t[0], (float)t[1], (float)t[2], (float)t[3]);
    }
    tile[ss][dd0] = v.x; tile[ss][dd0 + 1] = v.y;
    tile[ss][dd0 + 2] = v.z; tile[ss][dd0 + 3] = v.w;
  }
  __syncthreads();
#pragma unroll
  for (int it = 0; it < 4; it++) {
    int idx = it * 256 + threadIdx.x;
    int dd = idx >> 4, ss0 = (idx & 15) * 4;
    bf16x4 o;
#pragma unroll
    for (int e = 0; e < 4; e++) o[e] = (bf16)tile[ss0 + e][dd];
    *(bf16x4*)(vtall + ((size_t)bz * D_ + d0 + dd) * S_ + s0 + ss0) = o;
  }
}

// ---------------- flash attention (R13, best measured: 175.5 us) ----------------
__global__ __launch_bounds__(256, 2) void attn_kernel(const bf16* __restrict__ qbuf,
                                                      const bf16* __restrict__ k_all,
                                                      const bf16* __restrict__ vtall,
                                                      bf16* __restrict__ attnout) {
  __shared__ bf16 Ks[2 * 64 * 128];   // [key][d], 256B rows, swizzled 16B slots
  __shared__ bf16 Vs[2 * 64 * 128];   // paired rows: row r = {d=2r | d=2r+1}, 256B
  const int tid = threadIdx.x;
  const int wid = tid >> 6, lane = tid & 63;
  const int l31 = lane & 31, h = lane >> 5;
  const int xq = ((blockIdx.y >> 4) & 1) ? (15 - (int)blockIdx.x) : (int)blockIdx.x;
  const int q0 = xq * 128;
  const int bh = blockIdx.y;
  const int b = bh / H_, hh = bh % H_;
  const int hkv = hh / G_;
  const bf16* kb = k_all + (size_t)(b * HKV_ + hkv) * S_ * D_;
  const bf16* vb = vtall + (size_t)(b * HKV_ + hkv) * D_ * S_;
  const int qw = q0 + wid * 32;
  bf16x8 qf[8];
  {
    const bf16* qp = qbuf + ((size_t)(b * H_ + hh) * L_ + qw + l31) * D_ + h * 8;
#pragma unroll
    for (int ks = 0; ks < 8; ks++) qf[ks] = *(const bf16x8*)(qp + ks * 16);
  }
  f32x16 acc[4] = {};
  float mr = -3e38f, lr = 0.f;

  auto SK = [&](int buf, int s0) {
    char* kd = (char*)Ks + buf * 16384;
#pragma unroll
    for (int j = 0; j < 4; j++) {
      int cid = j * 256 + tid;
      int r = cid >> 4;
      int cl = (cid & 15) ^ (r & 15);
      gload16(kb + (size_t)(s0 + r) * D_ + cl * 8, (bf16*)(kd + (j * 256 + wid * 64) * 16));
    }
  };
  auto SV = [&](int buf, int s0) {
    char* vd = (char*)Vs + buf * 16384;
#pragma unroll
    for (int j = 0; j < 4; j++) {
      int cid = j * 256 + tid;
      int r = cid >> 4;
      int cl = (cid & 15) ^ (r & 15);
      gload16(vb + (size_t)(2 * r + (cl >> 3)) * S_ + s0 + (cl & 7) * 8,
              (bf16*)(vd + (j * 256 + wid * 64) * 16));
    }
  };

  auto QKT = [&](int buf, f32x16& o0, f32x16& o1) {
    char* kcur = (char*)Ks + buf * 16384;
    __builtin_amdgcn_s_setprio(1);
    {
      f32x16 a = {};
      int R = l31;
#pragma unroll
      for (int ks = 0; ks < 8; ks++) {
        int cl = 2 * ks + h;
        bf16x8 kf = *(const bf16x8*)(kcur + R * 256 + ((cl ^ (R & 15)) << 4));
        a = MFMA32(kf, qf[ks], a);
      }
      o0 = a;
    }
    {
      f32x16 a = {};
      int R = 32 + l31;
#pragma unroll
      for (int ks = 0; ks < 8; ks++) {
        int cl = 2 * ks + h;
        bf16x8 kf = *(const bf16x8*)(kcur + R * 256 + ((cl ^ (R & 15)) << 4));
        a = MFMA32(kf, qf[ks], a);
      }
      o1 = a;
    }
    __builtin_amdgcn_s_setprio(0);
  };

  auto FIN = [&](f32x16& st0, f32x16& st1, int s0, int vbuf) {
    char* vcur = (char*)Vs + vbuf * 16384;
    if (s0 + 63 > qw + SPAST_) {
      int q = qw + l31;
#pragma unroll
      for (int r = 0; r < 16; r++) {
        int key0 = s0 + (r & 3) + 8 * (r >> 2) + 4 * h;
        if (key0 > q + SPAST_) st0[r] = -1e30f;
        if (key0 + 32 > q + SPAST_) st1[r] = -1e30f;
      }
    }
    float t0 = fmaxf(fmaxf(st0[0], st0[1]), fmaxf(st0[2], st0[3]));
    float t1 = fmaxf(fmaxf(st0[4], st0[5]), fmaxf(st0[6], st0[7]));
    float t2 = fmaxf(fmaxf(st0[8], st0[9]), fmaxf(st0[10], st0[11]));
    float t3 = fmaxf(fmaxf(st0[12], st0[13]), fmaxf(st0[14], st0[15]));
    float u0 = fmaxf(fmaxf(st1[0], st1[1]), fmaxf(st1[2], st1[3]));
    float u1 = fmaxf(fmaxf(st1[4], st1[5]), fmaxf(st1[6], st1[7]));
    float u2 = fmaxf(fmaxf(st1[8], st1[9]), fmaxf(st1[10], st1[11]));
    float u3 = fmaxf(fmaxf(st1[12], st1[13]), fmaxf(st1[14], st1[15]));
    float mt = fmaxf(fmaxf(fmaxf(t0, t1), fmaxf(t2, t3)),
                     fmaxf(fmaxf(u0, u1), fmaxf(u2, u3)));
    mt = fmaxf(mt, __shfl_xor(mt, 32));
    if (__any(mt - mr > 8.0f)) {  // T13 defer-max
      float mn = fmaxf(mr, mt);
      float fac = exp2f(mr - mn);
      mr = mn;
      lr *= fac;
#pragma unroll
      for (int dt = 0; dt < 4; dt++) acc[dt] *= fac;
    }
    float sacc[4] = {0.f, 0.f, 0.f, 0.f};
#pragma unroll
    for (int r = 0; r < 16; r++) {
      float p = exp2f(st0[r] - mr);
      st0[r] = p;
      sacc[r & 3] += p;
    }
#pragma unroll
    for (int r = 0; r < 16; r++) {
      float p = exp2f(st1[r] - mr);
      st1[r] = p;
      sacc[r & 3] += p;
    }
    float s = (sacc[0] + sacc[1]) + (sacc[2] + sacc[3]);
    s += __shfl_xor(s, 32);
    lr += s;
    uint32_t W[2][8];
#pragma unroll
    for (int j = 0; j < 8; j++)
      asm("v_cvt_pk_bf16_f32 %0, %1, %2" : "=v"(W[0][j]) : "v"(st0[2 * j]), "v"(st0[2 * j + 1]));
#pragma unroll
    for (int j = 0; j < 8; j++)
      asm("v_cvt_pk_bf16_f32 %0, %1, %2" : "=v"(W[1][j]) : "v"(st1[2 * j]), "v"(st1[2 * j + 1]));
#pragma unroll
    for (int t = 0; t < 2; t++)
#pragma unroll
      for (int s4 = 0; s4 < 8; s4 += 4) {
        asm volatile("v_permlane32_swap_b32 %0, %1" : "+v"(W[t][s4 + 0]), "+v"(W[t][s4 + 2]));
        asm volatile("v_permlane32_swap_b32 %0, %1" : "+v"(W[t][s4 + 1]), "+v"(W[t][s4 + 3]));
      }
    __builtin_amdgcn_s_setprio(1);
#pragma unroll
    for (int dt = 0; dt < 4; dt++) {
      int r = dt * 16 + (l31 >> 1);
      int clb = 8 * (l31 & 1) + h;
      f32x16 a = acc[dt];
#pragma unroll
      for (int ks = 0; ks < 4; ks++) {
        int cl = clb + 2 * ks;
        bf16x8 vf = *(const bf16x8*)(vcur + r * 256 + ((cl ^ (r & 15)) << 4));
        union { uint32_t u[4]; bf16x8 v; } pb;
        pb.u[0] = W[ks >> 1][(ks & 1) * 4 + 0];
        pb.u[1] = W[ks >> 1][(ks & 1) * 4 + 1];
        pb.u[2] = W[ks >> 1][(ks & 1) * 4 + 2];
        pb.u[3] = W[ks >> 1][(ks & 1) * 4 + 3];
        a = MFMA32(vf, pb.v, a);
      }
      acc[dt] = a;
    }
    __builtin_amdgcn_s_setprio(0);
  };

  const int nchunk = (q0 + 128 + SPAST_) >> 6;  // 34 + 2*xq, always even
  const int smax_w = qw + 32 + SPAST_;

  SK(0, 0);
  SV(0, 0);
  SK(1, 64);
  asm volatile("s_waitcnt vmcnt(4)" ::: "memory");
  __builtin_amdgcn_s_barrier();
  f32x16 sA0, sA1, sB0, sB1;
  QKT(0, sA0, sA1);

  for (int i = 0; i < nchunk; i += 2) {
    asm volatile("s_waitcnt vmcnt(0)" ::: "memory");
    __builtin_amdgcn_s_barrier();
    if (i + 1 < nchunk && (i + 1) * 64 < smax_w) QKT((i + 1) & 1, sB0, sB1);
    if (i + 2 < nchunk) SK(i & 1, (i + 2) * 64);
    if (i + 1 < nchunk) SV((i + 1) & 1, (i + 1) * 64);
    if (i * 64 < smax_w) FIN(sA0, sA1, i * 64, i & 1);
    asm volatile("s_waitcnt vmcnt(0)" ::: "memory");
    __builtin_amdgcn_s_barrier();
    if (i + 2 < nchunk && (i + 2) * 64 < smax_w) QKT(i & 1, sA0, sA1);
    if (i + 3 < nchunk) SK((i + 1) & 1, (i + 3) * 64);
    if (i + 2 < nchunk) SV(i & 1, (i + 2) * 64);
    if ((i + 1) * 64 < smax_w) FIN(sB0, sB1, (i + 1) * 64, (i + 1) & 1);
  }
  {
    float inv = 1.0f / lr;
    int q = qw + l31;
    size_t base = ((size_t)(b * L_ + q) * H_ + hh) * D_;
#pragma unroll
    for (int dt = 0; dt < 4; dt++)
#pragma unroll
      for (int u = 0; u < 4; u++) {
        bf16x4 o;
#pragma unroll
        for (int e = 0; e < 4; e++) o[e] = (bf16)(acc[dt][4 * u + e] * inv);
        *(bf16x4*)(attnout + base + dt * 32 + 8 * u + 4 * h) = o;
      }
  }
}

extern "C" void kernel_launch(void* const* d_in, const int* in_sizes, int n_in,
                              void* d_out, int out_size, void* d_ws, size_t ws_size,
                              hipStream_t stream) {
  const float* x = (const float*)d_in[0];
  const float* wq = (const float*)d_in[1];
  const float* wk = (const float*)d_in[2];
  const float* wv = (const float*)d_in[3];
  const float* wo = (const float*)d_in[4];
  const float* bq = (const float*)d_in[5];
  const float* bk = (const float*)d_in[6];
  const float* bv = (const float*)d_in[7];
  const float* k_cache = (const float*)d_in[8];
  const float* v_cache = (const float*)d_in[9];
  const int* offp = (const int*)d_in[10];

  char* w = (char*)d_ws;
  size_t off = 0;
  auto alloc = [&](size_t bytes) -> char* {
    char* p = w + off;
    off += (bytes + 255) & ~(size_t)255;
    return p;
  };
  const size_t nBLE = (size_t)B_ * L_ * E_;
  const size_t nKV = (size_t)B_ * HKV_ * S_ * D_;
  bf16* xb = (bf16*)alloc(nBLE * 2);
  bf16* wqkvb = (bf16*)alloc((size_t)QKVN * E_ * 2);  // [wq; wk; wv] rows, (2560, 2048)
  bf16* wob = (bf16*)alloc((size_t)E_ * E_ * 2);
  bf16* qkv_lin = (bf16*)alloc((size_t)B_ * L_ * QKVN * 2);
  bf16* qbuf = (bf16*)alloc(nBLE * 2);
  bf16* k_all = (bf16*)alloc(nKV * 2);
  bf16* vtall = (bf16*)alloc(nKV * 2);
  bf16* attnout = (bf16*)alloc(nBLE * 2);
  float2* trig = (float2*)alloc((size_t)L_ * 64 * sizeof(float2));
  float* cbias = (float*)alloc(QKVN * sizeof(float));

  // fused conversions (x, wq, wk, wv -> wqkvb contiguous; wo) + trig + bias concat
  cvt5_kernel<<<17408, 256, 0, stream>>>(x, wq, wk, wv, wo, xb, wqkvb, wob);
  trig_kernel<<<L_, 64, 0, stream>>>(offp, trig);
  biascat_kernel<<<QKVN / 256, 256, 0, stream>>>(bq, bk, bv, cbias);

  const int M = B_ * L_;  // 4096
  // fused QKV projection: (4096 x 2048) @ (2560 x 2048)^T -> (4096 x 2560)
  gemm_nt<0><<<dim3(M / 128, QKVN / 128), 256, 0, stream>>>(xb, wqkvb, cbias, qkv_lin, M, QKVN, E_);
  rope_q_kernel<<<B_ * L_ / 2, 256, 0, stream>>>(qkv_lin, trig, qbuf);
  build_k_kernel<<<dim3(S_, B_ * HKV_), 128, 0, stream>>>(k_cache, qkv_lin, trig, k_all);
  build_vt_kernel<<<dim3(S_ / 64, D_ / 64, B_ * HKV_), 256, 0, stream>>>(v_cache, qkv_lin, vtall);
  attn_kernel<<<dim3(16, 32), 256, 0, stream>>>(qbuf, k_all, vtall, attnout);
  gemm_nt<1><<<dim3(M / 128, E_ / 128), 256, 0, stream>>>(attnout, wob, nullptr, d_out, M, E_, E_);
}